// Round 1
// baseline (4445.329 us; speedup 1.0000x reference)
//
#include <hip/hip_runtime.h>
#include <math.h>

// ---------------- constants ----------------
static constexpr int kB = 128;
static constexpr int kT = 50;

// ---------- generic transpose [N][O][C] -> [N][C][O] ----------
__global__ void k_transpose_oc(const float* __restrict__ in, float* __restrict__ out,
                               int N, int O, int C) {
    int idx = blockIdx.x * blockDim.x + threadIdx.x;
    int total = N * O * C;
    if (idx >= total) return;
    int o = idx % O; int t = idx / O; int c = t % C; int n = t / C;
    out[idx] = in[(n * O + o) * C + c];
}

// ---------- conv (Cin=1, Cout=8, VALID) + BN(eval) + ReLU ----------
__global__ void k_conv1_bn_relu(const float* __restrict__ in, const float* __restrict__ w,
                                const float* __restrict__ cb, const float* __restrict__ g,
                                const float* __restrict__ be, const float* __restrict__ m,
                                const float* __restrict__ v, float* __restrict__ out,
                                int Hin, int Win, int Hout, int Wout, int KH, int KW, int total) {
    int idx = blockIdx.x * blockDim.x + threadIdx.x;
    if (idx >= total) return;
    int ox = idx % Wout; int t = idx / Wout;
    int oy = t % Hout; t /= Hout;
    int oc = t % 8; int b = t / 8;
    const float* ip = in + (b * Hin + oy) * Win + ox;
    const float* wp = w + oc * KH * KW;
    float acc = 0.f;
    for (int ky = 0; ky < KH; ++ky)
        for (int kx = 0; kx < KW; ++kx)
            acc += ip[ky * Win + kx] * wp[ky * KW + kx];
    float s = g[oc] * rsqrtf(v[oc] + 1e-5f);
    float bias = (cb[oc] - m[oc]) * s + be[oc];
    out[idx] = fmaxf(acc * s + bias, 0.f);
}

// ---------- half-pixel bilinear resize (no antialias) + channel concat ----------
// out: [128,24,25,156]; ch 0-7 from xa (196x39), 8-15 from xb (199x35), 16-23 from xc (199x35)
__global__ void k_resize_concat(const float* __restrict__ xa, const float* __restrict__ xb,
                                const float* __restrict__ xc, float* __restrict__ out, int total) {
    int idx = blockIdx.x * blockDim.x + threadIdx.x;
    if (idx >= total) return;
    int ox = idx % 156; int t = idx / 156;
    int oy = t % 25; t /= 25;
    int ch = t % 24; int b = t / 24;
    int grp = ch >> 3, c = ch & 7;
    const float* src; int Hin, Win;
    if (grp == 0) { src = xa; Hin = 196; Win = 39; }
    else          { src = (grp == 1 ? xb : xc); Hin = 199; Win = 35; }
    float sy = (oy + 0.5f) * ((float)Hin / 25.f) - 0.5f;
    float sx = (ox + 0.5f) * ((float)Win / 156.f) - 0.5f;
    float fy0 = floorf(sy), fx0 = floorf(sx);
    float fy = sy - fy0, fx = sx - fx0;
    int y0 = (int)fy0, x0 = (int)fx0;
    int y0c = min(max(y0, 0), Hin - 1), y1c = min(max(y0 + 1, 0), Hin - 1);
    int x0c = min(max(x0, 0), Win - 1), x1c = min(max(x0 + 1, 0), Win - 1);
    const float* p = src + (size_t)(b * 8 + c) * Hin * Win;
    float v00 = p[y0c * Win + x0c], v01 = p[y0c * Win + x1c];
    float v10 = p[y1c * Win + x0c], v11 = p[y1c * Win + x1c];
    out[idx] = v00 * (1.f - fy) * (1.f - fx) + v01 * (1.f - fy) * fx
             + v10 * fy * (1.f - fx) + v11 * fy * fx;
}

// ---------- 3x3 conv, pad 1, fused BN(eval) + ReLU ----------
__global__ void k_conv3_bn_relu(const float* __restrict__ in, const float* __restrict__ w,
                                const float* __restrict__ cb, const float* __restrict__ g,
                                const float* __restrict__ be, const float* __restrict__ m,
                                const float* __restrict__ v, float* __restrict__ out,
                                int Cin, int Cout, int H, int W, int total) {
    int idx = blockIdx.x * blockDim.x + threadIdx.x;
    if (idx >= total) return;
    int ox = idx % W; int t = idx / W;
    int oy = t % H; t /= H;
    int oc = t % Cout; int b = t / Cout;
    float acc = 0.f;
    const float* wb = w + (size_t)oc * Cin * 9;
    for (int ci = 0; ci < Cin; ++ci) {
        const float* ib = in + ((size_t)(b * Cin + ci) * H) * W;
        const float* wr = wb + ci * 9;
        #pragma unroll
        for (int ky = 0; ky < 3; ++ky) {
            int iy = oy + ky - 1;
            if (iy < 0 || iy >= H) continue;
            const float* irow = ib + iy * W;
            #pragma unroll
            for (int kx = 0; kx < 3; ++kx) {
                int ix = ox + kx - 1;
                if (ix < 0 || ix >= W) continue;
                acc += irow[ix] * wr[ky * 3 + kx];
            }
        }
    }
    float s = g[oc] * rsqrtf(v[oc] + 1e-5f);
    float bias = (cb[oc] - m[oc]) * s + be[oc];
    out[idx] = fmaxf(acc * s + bias, 0.f);
}

// ---------- 2x2 maxpool stride 2 (VALID) ----------
__global__ void k_maxpool(const float* __restrict__ in, float* __restrict__ out,
                          int C, int Hin, int Win, int Hout, int Wout, int total) {
    int idx = blockIdx.x * blockDim.x + threadIdx.x;
    if (idx >= total) return;
    int ox = idx % Wout; int t = idx / Wout;
    int oy = t % Hout; t /= Hout;
    int c = t % C; int b = t / C;
    const float* p = in + ((size_t)(b * C + c) * Hin + 2 * oy) * Win + 2 * ox;
    float m0 = fmaxf(p[0], p[1]);
    float m1 = fmaxf(p[Win], p[Win + 1]);
    out[idx] = fmaxf(m0, m1);
}

// ---------- fused audio attention (both stages) + spatial GAP ----------
// x: [128,96,6,39] (S=234). grid (b=128, n=8, stage=2), block 128 (96 active for compute).
// Per position: q/k/v = per-head 96x96 matvec; softmax over o-axis (96); out += softmax*v.
// Weights are pre-transposed to [n][c][o] for coalesced lane access.
__global__ void __launch_bounds__(128) k_audio_attn(
    const float* __restrict__ x,
    const float* __restrict__ wq1, const float* __restrict__ bq1,
    const float* __restrict__ wk1, const float* __restrict__ bk1,
    const float* __restrict__ wv1, const float* __restrict__ bv1,
    const float* __restrict__ wq2, const float* __restrict__ bq2,
    const float* __restrict__ wk2, const float* __restrict__ bk2,
    const float* __restrict__ wv2, const float* __restrict__ bv2,
    float* __restrict__ afeat) {
    int b = blockIdx.x, n = blockIdx.y, stage = blockIdx.z;
    const float* wq = stage ? wq2 : wq1; const float* bq = stage ? bq2 : bq1;
    const float* wk = stage ? wk2 : wk1; const float* bk = stage ? bk2 : bk1;
    const float* wv = stage ? wv2 : wv1; const float* bv = stage ? bv2 : bv1;
    __shared__ float xt[96 * 26];
    __shared__ float sb[96 * 26];
    __shared__ float mx[26], sm[26];
    int tid = threadIdx.x;
    int o = tid;
    float bqv = 0.f, bkv = 0.f, bvv = 0.f;
    const float *wqb = wq, *wkb = wk, *wvb = wv;
    if (o < 96) {
        bqv = bq[n * 96 + o]; bkv = bk[n * 96 + o]; bvv = bv[n * 96 + o];
        wqb = wq + n * 9216 + o; wkb = wk + n * 9216 + o; wvb = wv + n * 9216 + o;
    }
    float accO = 0.f;
    const float* xb = x + (size_t)b * 96 * 234;
    for (int tile = 0; tile < 9; ++tile) {
        int p0 = tile * 26;
        for (int e = tid; e < 96 * 26; e += 128) {
            int c = e / 26, pp = e - c * 26;
            xt[e] = xb[c * 234 + p0 + pp];
        }
        __syncthreads();
        float av[26];
        if (o < 96) {
            float aq[26], ak[26];
            #pragma unroll
            for (int p = 0; p < 26; ++p) { aq[p] = 0.f; ak[p] = 0.f; av[p] = 0.f; }
            for (int c = 0; c < 96; ++c) {
                float wqv = wqb[c * 96], wkv = wkb[c * 96], wvv2 = wvb[c * 96];
                const float* xr = xt + c * 26;
                #pragma unroll
                for (int p = 0; p < 26; ++p) {
                    float xv = xr[p];
                    aq[p] += wqv * xv; ak[p] += wkv * xv; av[p] += wvv2 * xv;
                }
            }
            #pragma unroll
            for (int p = 0; p < 26; ++p)
                sb[o * 26 + p] = (aq[p] + bqv) * (ak[p] + bkv);
        }
        __syncthreads();
        if (tid < 26) {
            float mxv = -1e30f;
            for (int oo = 0; oo < 96; ++oo) mxv = fmaxf(mxv, sb[oo * 26 + tid]);
            float s = 0.f;
            for (int oo = 0; oo < 96; ++oo) s += expf(sb[oo * 26 + tid] - mxv);
            mx[tid] = mxv; sm[tid] = s;
        }
        __syncthreads();
        if (o < 96) {
            #pragma unroll
            for (int p = 0; p < 26; ++p)
                accO += expf(sb[o * 26 + p] - mx[p]) / sm[p] * (av[p] + bvv);
        }
        __syncthreads();
    }
    if (o < 96) afeat[b * 1536 + n * 192 + stage * 96 + o] = accO * (1.f / 234.f);
}

// ---------- global average pool over 234 spatial positions ----------
__global__ void k_gap(const float* __restrict__ x, float* __restrict__ xgap) {
    int b = blockIdx.x; int c = threadIdx.x;
    if (c >= 96) return;
    const float* p = x + (size_t)(b * 96 + c) * 234;
    float s = 0.f;
    for (int i = 0; i < 234; ++i) s += p[i];
    xgap[b * 96 + c] = s * (1.f / 234.f);
}

// ---------- embedding lookup + input-side GRU GEMM (gi for all t) ----------
// GI[(b*T+t)*300 + j] = b_ih[j] + emb[tok[b,t],:] . w_ih[j,:]   (w_ih pre-transposed [k][j])
__global__ void k_gi(const int* __restrict__ tokens, const float* __restrict__ emb,
                     const float* __restrict__ wiht, const float* __restrict__ b_ih,
                     float* __restrict__ GI) {
    int bt = blockIdx.x;
    __shared__ float er[200];
    int tok = tokens[bt];
    for (int k = threadIdx.x; k < 200; k += 256) er[k] = emb[(size_t)tok * 200 + k];
    __syncthreads();
    for (int j = threadIdx.x; j < 300; j += 256) {
        float acc = b_ih[j];
        for (int k = 0; k < 200; ++k) acc += wiht[k * 300 + j] * er[k];
        GI[(size_t)bt * 300 + j] = acc;
    }
}

// ---------- one GRU time step (torch gate order r,z,n; b_hn inside r-gating) ----------
__global__ void __launch_bounds__(320) k_gru_step(const float* __restrict__ GI,
        const float* __restrict__ whht, const float* __restrict__ b_hh,
        float* __restrict__ outs, int t) {
    int b = blockIdx.x; int tid = threadIdx.x;
    __shared__ float hprev[100];
    __shared__ float gI[300], gH[300];
    if (tid < 100) hprev[tid] = (t == 0) ? 0.f : outs[(size_t)(b * kT + t - 1) * 100 + tid];
    __syncthreads();
    if (tid < 300) {
        float acc = b_hh[tid];
        for (int k = 0; k < 100; ++k) acc += whht[k * 300 + tid] * hprev[k];
        gH[tid] = acc;
        gI[tid] = GI[(size_t)(b * kT + t) * 300 + tid];
    }
    __syncthreads();
    if (tid < 100) {
        float r = 1.f / (1.f + expf(-(gI[tid] + gH[tid])));
        float z = 1.f / (1.f + expf(-(gI[100 + tid] + gH[100 + tid])));
        float nn = tanhf(gI[200 + tid] + r * gH[200 + tid]);
        float h2 = (1.f - z) * nn + z * hprev[tid];
        outs[(size_t)(b * kT + t) * 100 + tid] = h2;
    }
}

// ---------- fused text attention (both stages), summed over T in-kernel ----------
// grid (b=128, stage=2, n=8), block 128 (96 active). Weights pre-transposed [n][c][o].
__global__ void __launch_bounds__(128) k_text_attn(const float* __restrict__ outs,
    const float* __restrict__ wq1, const float* __restrict__ bq1,
    const float* __restrict__ wk1, const float* __restrict__ bk1,
    const float* __restrict__ wv1, const float* __restrict__ bv1,
    const float* __restrict__ wq2, const float* __restrict__ bq2,
    const float* __restrict__ wk2, const float* __restrict__ bk2,
    const float* __restrict__ wv2, const float* __restrict__ bv2,
    float* __restrict__ tfeat) {
    int b = blockIdx.x, stage = blockIdx.y, n = blockIdx.z;
    const float* wq = stage ? wq2 : wq1; const float* bq = stage ? bq2 : bq1;
    const float* wk = stage ? wk2 : wk1; const float* bk = stage ? bk2 : bk1;
    const float* wv = stage ? wv2 : wv1; const float* bv = stage ? bv2 : bv1;
    int tid = threadIdx.x;
    __shared__ float row[100];
    __shared__ float sb[96];
    __shared__ float red[2];
    float acc = 0.f;
    float bqv = 0.f, bkv = 0.f, bvv = 0.f;
    const float *wqb = wq, *wkb = wk, *wvb = wv;
    if (tid < 96) {
        bqv = bq[n * 96 + tid]; bkv = bk[n * 96 + tid]; bvv = bv[n * 96 + tid];
        wqb = wq + n * 9600 + tid; wkb = wk + n * 9600 + tid; wvb = wv + n * 9600 + tid;
    }
    for (int t = 0; t < kT; ++t) {
        __syncthreads();
        for (int k = tid; k < 100; k += 128) row[k] = outs[(size_t)(b * kT + t) * 100 + k];
        __syncthreads();
        float s = 0.f, vv = 0.f;
        if (tid < 96) {
            float q = bqv, kk = bkv, v_ = bvv;
            for (int c = 0; c < 100; ++c) {
                float xv = row[c];
                q += wqb[c * 96] * xv; kk += wkb[c * 96] * xv; v_ += wvb[c * 96] * xv;
            }
            s = q * kk; vv = v_;
            sb[tid] = s;
        }
        __syncthreads();
        if (tid == 0) {
            float mxv = -1e30f;
            for (int oo = 0; oo < 96; ++oo) mxv = fmaxf(mxv, sb[oo]);
            float smv = 0.f;
            for (int oo = 0; oo < 96; ++oo) smv += expf(sb[oo] - mxv);
            red[0] = mxv; red[1] = smv;
        }
        __syncthreads();
        if (tid < 96) acc += expf(s - red[0]) / red[1] * vv;
    }
    if (tid < 96) tfeat[b * 1536 + stage * 768 + n * 96 + tid] = acc;
}

// ---------- cross-modal gated fusion + final logits ----------
__global__ void __launch_bounds__(128) k_final(const float* __restrict__ xgap,
    const float* __restrict__ outs, const float* __restrict__ afeat,
    const float* __restrict__ tfeat,
    const float* __restrict__ w_fa, const float* __restrict__ b_fa,
    const float* __restrict__ w_ft, const float* __restrict__ b_ft,
    const float* __restrict__ w_e, const float* __restrict__ b_e,
    float* __restrict__ out) {
    int b = blockIdx.x; int tid = threadIdx.x;
    __shared__ float xg[96], hv[100], st[100], sa[96], aat[96], atba[100];
    __shared__ float redm[2], reds[2];
    if (tid < 96) xg[tid] = xgap[b * 96 + tid];
    if (tid < 100) hv[tid] = outs[(size_t)(b * kT + kT - 1) * 100 + tid];
    __syncthreads();
    if (tid < 100) {
        float acc = b_fa[tid];
        const float* wr = w_fa + tid * 96;
        for (int c = 0; c < 96; ++c) acc += wr[c] * xg[c];
        st[tid] = acc;
    }
    if (tid < 96) {
        float acc = b_ft[tid];
        const float* wr = w_ft + tid * 100;
        for (int c = 0; c < 100; ++c) acc += wr[c] * hv[c];
        sa[tid] = acc;
    }
    __syncthreads();
    if (tid == 0) {
        float mxv = -1e30f; for (int i = 0; i < 100; ++i) mxv = fmaxf(mxv, st[i]);
        float s = 0.f; for (int i = 0; i < 100; ++i) s += expf(st[i] - mxv);
        redm[0] = mxv; reds[0] = s;
    }
    if (tid == 1) {
        float mxv = -1e30f; for (int i = 0; i < 96; ++i) mxv = fmaxf(mxv, sa[i]);
        float s = 0.f; for (int i = 0; i < 96; ++i) s += expf(sa[i] - mxv);
        redm[1] = mxv; reds[1] = s;
    }
    __syncthreads();
    if (tid < 100) atba[tid] = expf(st[tid] - redm[0]) / reds[0] * hv[tid];
    if (tid < 96)  aat[tid]  = expf(sa[tid] - redm[1]) / reds[1] * xg[tid];
    __syncthreads();
    float a0 = 0.f, a1 = 0.f, a2 = 0.f, a3 = 0.f;
    for (int col = tid; col < 3268; col += 128) {
        float f;
        if (col < 1536)      f = afeat[b * 1536 + col];
        else if (col < 3072) f = tfeat[b * 1536 + col - 1536];
        else if (col < 3168) f = aat[col - 3072];
        else                 f = atba[col - 3168];
        a0 += w_e[col] * f;            a1 += w_e[3268 + col] * f;
        a2 += w_e[2 * 3268 + col] * f; a3 += w_e[3 * 3268 + col] * f;
    }
    __shared__ float r4[4][128];
    r4[0][tid] = a0; r4[1][tid] = a1; r4[2][tid] = a2; r4[3][tid] = a3;
    __syncthreads();
    if (tid < 4) {
        float s = 0.f;
        for (int i = 0; i < 128; ++i) s += r4[tid][i];
        out[b * 4 + tid] = s + b_e[tid];
    }
}

// =====================================================================
extern "C" void kernel_launch(void* const* d_in, const int* in_sizes, int n_in,
                              void* d_out, int out_size, void* d_ws, size_t ws_size,
                              hipStream_t stream) {
    (void)in_sizes; (void)n_in; (void)out_size; (void)ws_size;
    const float* mfcc_t = (const float*)d_in[0];
    const float* mfcc_f = (const float*)d_in[1];
    const float* mfcc_c = (const float*)d_in[2];
    const int*   tokens = (const int*)d_in[3];
    // d_in[4] = lengths (all == T, unused)
    const float *w1a = (const float*)d_in[5],  *b1a = (const float*)d_in[6],
                *g1a = (const float*)d_in[7],  *be1a = (const float*)d_in[8],
                *m1a = (const float*)d_in[9],  *v1a = (const float*)d_in[10];
    const float *w1b = (const float*)d_in[11], *b1b = (const float*)d_in[12],
                *g1b = (const float*)d_in[13], *be1b = (const float*)d_in[14],
                *m1b = (const float*)d_in[15], *v1b = (const float*)d_in[16];
    const float *w2 = (const float*)d_in[17], *b2 = (const float*)d_in[18],
                *g2 = (const float*)d_in[19], *be2 = (const float*)d_in[20],
                *m2 = (const float*)d_in[21], *v2 = (const float*)d_in[22];
    const float *w3 = (const float*)d_in[23], *b3 = (const float*)d_in[24],
                *g3 = (const float*)d_in[25], *be3 = (const float*)d_in[26],
                *m3 = (const float*)d_in[27], *v3 = (const float*)d_in[28];
    const float *w4 = (const float*)d_in[29], *b4 = (const float*)d_in[30],
                *g4 = (const float*)d_in[31], *be4 = (const float*)d_in[32],
                *m4 = (const float*)d_in[33], *v4 = (const float*)d_in[34];
    const float *wq_a1 = (const float*)d_in[35], *bq_a1 = (const float*)d_in[36],
                *wk_a1 = (const float*)d_in[37], *bk_a1 = (const float*)d_in[38],
                *wv_a1 = (const float*)d_in[39], *bv_a1 = (const float*)d_in[40];
    const float *wq_a2 = (const float*)d_in[41], *bq_a2 = (const float*)d_in[42],
                *wk_a2 = (const float*)d_in[43], *bk_a2 = (const float*)d_in[44],
                *wv_a2 = (const float*)d_in[45], *bv_a2 = (const float*)d_in[46];
    const float *emb  = (const float*)d_in[47];
    const float *w_ih = (const float*)d_in[48], *w_hh = (const float*)d_in[49],
                *b_ih = (const float*)d_in[50], *b_hh = (const float*)d_in[51];
    const float *wq_t1 = (const float*)d_in[52], *bq_t1 = (const float*)d_in[53],
                *wk_t1 = (const float*)d_in[54], *bk_t1 = (const float*)d_in[55],
                *wv_t1 = (const float*)d_in[56], *bv_t1 = (const float*)d_in[57];
    const float *wq_t2 = (const float*)d_in[58], *bq_t2 = (const float*)d_in[59],
                *wk_t2 = (const float*)d_in[60], *bk_t2 = (const float*)d_in[61],
                *wv_t2 = (const float*)d_in[62], *bv_t2 = (const float*)d_in[63];
    const float *w_fa = (const float*)d_in[64], *b_fa = (const float*)d_in[65],
                *w_ft = (const float*)d_in[66], *b_ft = (const float*)d_in[67],
                *w_e  = (const float*)d_in[68], *b_e  = (const float*)d_in[69];

    float* ws = (float*)d_ws;
    // ----- workspace arena (floats). Peak ~36.1M floats (~144.5 MB), zones reused. -----
    const size_t Z0 = 0;                 // 22,091,776 : xa|xb|xc -> c2 -> c3 -> x4
    const size_t Z1 = 22091776ull;       // 11,980,800 : x1 -> p2 -> p3 -> GI
    const size_t OUTS  = 34072576ull;    //    640,000 : GRU outputs [B*T,100]
    const size_t AFEAT = 34712576ull;    //    196,608
    const size_t TFEAT = 34909184ull;    //    196,608
    const size_t XGAP  = 35105792ull;    //     12,288
    const size_t WT    = 35118080ull;    //    993,168 : transposed weights
    float* XA = ws + Z0;
    float* XB = ws + Z0 + 7827456ull;
    float* XC = ws + Z0 + 14959616ull;
    float* X1 = ws + Z1;
    float* C2 = ws + Z0;  float* P2 = ws + Z1;
    float* C3 = ws + Z0;  float* P3 = ws + Z1;
    float* X4 = ws + Z0;  float* GI = ws + Z1;
    float* outs  = ws + OUTS;
    float* afeat = ws + AFEAT;
    float* tfeat = ws + TFEAT;
    float* xgap  = ws + XGAP;
    float* wqa1t = ws + WT;
    float* wka1t = wqa1t + 73728; float* wva1t = wka1t + 73728;
    float* wqa2t = wva1t + 73728; float* wka2t = wqa2t + 73728; float* wva2t = wka2t + 73728;
    float* wqt1t = wva2t + 73728;
    float* wkt1t = wqt1t + 76800; float* wvt1t = wkt1t + 76800;
    float* wqt2t = wvt1t + 76800; float* wkt2t = wqt2t + 76800; float* wvt2t = wkt2t + 76800;
    float* wiht  = wvt2t + 76800;   // 60,000
    float* whht  = wiht + 60000;    // 30,000

    // ----- weight transposes (coalesced matvec layout) -----
    k_transpose_oc<<<288, 256, 0, stream>>>(wq_a1, wqa1t, 8, 96, 96);
    k_transpose_oc<<<288, 256, 0, stream>>>(wk_a1, wka1t, 8, 96, 96);
    k_transpose_oc<<<288, 256, 0, stream>>>(wv_a1, wva1t, 8, 96, 96);
    k_transpose_oc<<<288, 256, 0, stream>>>(wq_a2, wqa2t, 8, 96, 96);
    k_transpose_oc<<<288, 256, 0, stream>>>(wk_a2, wka2t, 8, 96, 96);
    k_transpose_oc<<<288, 256, 0, stream>>>(wv_a2, wva2t, 8, 96, 96);
    k_transpose_oc<<<300, 256, 0, stream>>>(wq_t1, wqt1t, 8, 96, 100);
    k_transpose_oc<<<300, 256, 0, stream>>>(wk_t1, wkt1t, 8, 96, 100);
    k_transpose_oc<<<300, 256, 0, stream>>>(wv_t1, wvt1t, 8, 96, 100);
    k_transpose_oc<<<300, 256, 0, stream>>>(wq_t2, wqt2t, 8, 96, 100);
    k_transpose_oc<<<300, 256, 0, stream>>>(wk_t2, wkt2t, 8, 96, 100);
    k_transpose_oc<<<300, 256, 0, stream>>>(wv_t2, wvt2t, 8, 96, 100);
    k_transpose_oc<<<235, 256, 0, stream>>>(w_ih, wiht, 1, 300, 200);
    k_transpose_oc<<<118, 256, 0, stream>>>(w_hh, whht, 1, 300, 100);

    // ----- audio CNN stem -----
    k_conv1_bn_relu<<<30576, 256, 0, stream>>>(mfcc_t, w1a, b1a, g1a, be1a, m1a, v1a,
                                               XA, 200, 40, 196, 39, 5, 2, 7827456);
    k_conv1_bn_relu<<<27860, 256, 0, stream>>>(mfcc_f, w1b, b1b, g1b, be1b, m1b, v1b,
                                               XB, 200, 40, 199, 35, 2, 6, 7132160);
    k_conv1_bn_relu<<<27860, 256, 0, stream>>>(mfcc_c, w1b, b1b, g1b, be1b, m1b, v1b,
                                               XC, 200, 40, 199, 35, 2, 6, 7132160);
    k_resize_concat<<<46800, 256, 0, stream>>>(XA, XB, XC, X1, 11980800);
    k_conv3_bn_relu<<<62400, 256, 0, stream>>>(X1, w2, b2, g2, be2, m2, v2, C2,
                                               24, 32, 25, 156, 15974400);
    k_maxpool<<<14976, 256, 0, stream>>>(C2, P2, 32, 25, 156, 12, 78, 3833856);
    k_conv3_bn_relu<<<29952, 256, 0, stream>>>(P2, w3, b3, g3, be3, m3, v3, C3,
                                               32, 64, 12, 78, 7667712);
    k_maxpool<<<7488, 256, 0, stream>>>(C3, P3, 64, 12, 78, 6, 39, 1916928);
    k_conv3_bn_relu<<<11232, 256, 0, stream>>>(P3, w4, b4, g4, be4, m4, v4, X4,
                                               64, 96, 6, 39, 2875392);

    // ----- audio attention + GAP (reads X4) -----
    k_audio_attn<<<dim3(kB, 8, 2), 128, 0, stream>>>(X4,
        wqa1t, bq_a1, wka1t, bk_a1, wva1t, bv_a1,
        wqa2t, bq_a2, wka2t, bk_a2, wva2t, bv_a2, afeat);
    k_gap<<<kB, 128, 0, stream>>>(X4, xgap);

    // ----- text branch (GI overwrites P3 region only after conv4 consumed it) -----
    k_gi<<<kB * kT, 256, 0, stream>>>(tokens, emb, wiht, b_ih, GI);
    for (int t = 0; t < kT; ++t)
        k_gru_step<<<kB, 320, 0, stream>>>(GI, whht, b_hh, outs, t);
    k_text_attn<<<dim3(kB, 2, 8), 128, 0, stream>>>(outs,
        wqt1t, bq_t1, wkt1t, bk_t1, wvt1t, bv_t1,
        wqt2t, bq_t2, wkt2t, bk_t2, wvt2t, bv_t2, tfeat);

    // ----- fusion + logits -----
    k_final<<<kB, 128, 0, stream>>>(xgap, outs, afeat, tfeat,
                                    w_fa, b_fa, w_ft, b_ft, w_e, b_e, (float*)d_out);
}

// Round 2
// 2416.195 us; speedup vs baseline: 1.8398x; 1.8398x over previous
//
#include <hip/hip_runtime.h>
#include <math.h>

// ---------------- constants ----------------
static constexpr int kB = 128;
static constexpr int kT = 50;

// ---------- generic transpose [N][O][C] -> [N][C][O] ----------
__global__ void k_transpose_oc(const float* __restrict__ in, float* __restrict__ out,
                               int N, int O, int C) {
    int idx = blockIdx.x * blockDim.x + threadIdx.x;
    int total = N * O * C;
    if (idx >= total) return;
    int o = idx % O; int t = idx / O; int c = t % C; int n = t / C;
    out[idx] = in[(n * O + o) * C + c];
}

// ---------- conv weight transpose [OC][CI][3][3] -> [(ci*9+k)][oc] ----------
__global__ void k_transpose_convw(const float* __restrict__ w, float* __restrict__ wT,
                                  int CIN, int COUT) {
    int idx = blockIdx.x * blockDim.x + threadIdx.x;
    int total = COUT * CIN * 9;
    if (idx >= total) return;
    int oc = idx % COUT;
    int rk = idx / COUT;   // ci*9 + k
    wT[idx] = w[oc * CIN * 9 + rk];
}

// ---------- conv (Cin=1, Cout=8, VALID) + BN(eval) + ReLU ----------
__global__ void k_conv1_bn_relu(const float* __restrict__ in, const float* __restrict__ w,
                                const float* __restrict__ cb, const float* __restrict__ g,
                                const float* __restrict__ be, const float* __restrict__ m,
                                const float* __restrict__ v, float* __restrict__ out,
                                int Hin, int Win, int Hout, int Wout, int KH, int KW, int total) {
    int idx = blockIdx.x * blockDim.x + threadIdx.x;
    if (idx >= total) return;
    int ox = idx % Wout; int t = idx / Wout;
    int oy = t % Hout; t /= Hout;
    int oc = t % 8; int b = t / 8;
    const float* ip = in + (b * Hin + oy) * Win + ox;
    const float* wp = w + oc * KH * KW;
    float acc = 0.f;
    for (int ky = 0; ky < KH; ++ky)
        for (int kx = 0; kx < KW; ++kx)
            acc += ip[ky * Win + kx] * wp[ky * KW + kx];
    float s = g[oc] * rsqrtf(v[oc] + 1e-5f);
    float bias = (cb[oc] - m[oc]) * s + be[oc];
    out[idx] = fmaxf(acc * s + bias, 0.f);
}

// ---------- half-pixel bilinear resize (no antialias) + channel concat ----------
__global__ void k_resize_concat(const float* __restrict__ xa, const float* __restrict__ xb,
                                const float* __restrict__ xc, float* __restrict__ out, int total) {
    int idx = blockIdx.x * blockDim.x + threadIdx.x;
    if (idx >= total) return;
    int ox = idx % 156; int t = idx / 156;
    int oy = t % 25; t /= 25;
    int ch = t % 24; int b = t / 24;
    int grp = ch >> 3, c = ch & 7;
    const float* src; int Hin, Win;
    if (grp == 0) { src = xa; Hin = 196; Win = 39; }
    else          { src = (grp == 1 ? xb : xc); Hin = 199; Win = 35; }
    float sy = (oy + 0.5f) * ((float)Hin / 25.f) - 0.5f;
    float sx = (ox + 0.5f) * ((float)Win / 156.f) - 0.5f;
    float fy0 = floorf(sy), fx0 = floorf(sx);
    float fy = sy - fy0, fx = sx - fx0;
    int y0 = (int)fy0, x0 = (int)fx0;
    int y0c = min(max(y0, 0), Hin - 1), y1c = min(max(y0 + 1, 0), Hin - 1);
    int x0c = min(max(x0, 0), Win - 1), x1c = min(max(x0 + 1, 0), Win - 1);
    const float* p = src + (size_t)(b * 8 + c) * Hin * Win;
    float v00 = p[y0c * Win + x0c], v01 = p[y0c * Win + x1c];
    float v10 = p[y1c * Win + x0c], v11 = p[y1c * Win + x1c];
    out[idx] = v00 * (1.f - fy) * (1.f - fx) + v01 * (1.f - fy) * fx
             + v10 * fy * (1.f - fx) + v11 * fy * fx;
}

// ---------- LDS-tiled 3x3 conv, pad 1, fused BN(eval) + ReLU ----------
// grid: (B, ceil(H/ROWS), COUT/8). block 256.
// Stages CI_T input channels (with zero-padded halo) + 8-oc weight slice in LDS.
// Each thread: NPX pixels (strided by 256) x 8 oc register tile.
template<int CIN, int CI_T, int H, int W, int ROWS, int NPX>
__global__ void __launch_bounds__(256) k_conv3x3_tiled(
    const float* __restrict__ in, const float* __restrict__ wT,
    const float* __restrict__ cb, const float* __restrict__ g,
    const float* __restrict__ be, const float* __restrict__ m,
    const float* __restrict__ v, float* __restrict__ out, int COUT) {
    constexpr int WP = W + 2;
    constexpr int RP = ROWS + 2;
    constexpr int STAGE = CI_T * RP * WP;
    __shared__ float sx[STAGE];
    __shared__ float sw[CI_T * 9 * 8];
    const int b = blockIdx.x, rt = blockIdx.y, oc0 = blockIdx.z * 8;
    const int row0 = rt * ROWS;
    const int tid = threadIdx.x;

    int off[NPX]; bool val[NPX];
    #pragma unroll
    for (int j = 0; j < NPX; ++j) {
        int px = tid + j * 256;
        int oy = px / W, ox = px - oy * W;
        bool ok = (px < ROWS * W) && (row0 + oy < H);
        val[j] = ok;
        off[j] = ok ? (oy * WP + ox) : 0;
    }

    float acc[NPX][8];
    #pragma unroll
    for (int j = 0; j < NPX; ++j)
        #pragma unroll
        for (int o = 0; o < 8; ++o) acc[j][o] = 0.f;

    for (int c0 = 0; c0 < CIN; c0 += CI_T) {
        __syncthreads();
        // stage input chunk (coalesced along xx)
        for (int e = tid; e < STAGE; e += 256) {
            int ci = e / (RP * WP);
            int rem = e - ci * RP * WP;
            int r = rem / WP;
            int xx = rem - r * WP;
            int iy = row0 - 1 + r;
            int ix = xx - 1;
            float vv = 0.f;
            if (iy >= 0 && iy < H && ix >= 0 && ix < W)
                vv = in[((size_t)(b * CIN + c0 + ci) * H + iy) * W + ix];
            sx[e] = vv;
        }
        // stage weight slice: sw[(ci_l*9+k)*8 + o] = wT[((c0+ci_l)*9+k)*COUT + oc0+o]
        for (int e = tid; e < CI_T * 9 * 8; e += 256) {
            int rk = e >> 3;
            int o = e & 7;
            sw[e] = wT[((size_t)c0 * 9 + rk) * COUT + oc0 + o];
        }
        __syncthreads();
        #pragma unroll 1
        for (int cl = 0; cl < CI_T; ++cl) {
            const float* sxc = sx + cl * RP * WP;
            #pragma unroll
            for (int k = 0; k < 9; ++k) {
                const int ky = k / 3, kx = k % 3;
                const float4 wa = *(const float4*)(sw + (cl * 9 + k) * 8);
                const float4 wb = *(const float4*)(sw + (cl * 9 + k) * 8 + 4);
                #pragma unroll
                for (int j = 0; j < NPX; ++j) {
                    float xv = sxc[off[j] + ky * WP + kx];
                    acc[j][0] += xv * wa.x; acc[j][1] += xv * wa.y;
                    acc[j][2] += xv * wa.z; acc[j][3] += xv * wa.w;
                    acc[j][4] += xv * wb.x; acc[j][5] += xv * wb.y;
                    acc[j][6] += xv * wb.z; acc[j][7] += xv * wb.w;
                }
            }
        }
    }
    float sc[8], bi[8];
    #pragma unroll
    for (int o = 0; o < 8; ++o) {
        float s = g[oc0 + o] * rsqrtf(v[oc0 + o] + 1e-5f);
        sc[o] = s; bi[o] = (cb[oc0 + o] - m[oc0 + o]) * s + be[oc0 + o];
    }
    #pragma unroll
    for (int j = 0; j < NPX; ++j) if (val[j]) {
        int px = tid + j * 256;
        int oy = row0 + px / W, ox = px % W;
        #pragma unroll
        for (int o = 0; o < 8; ++o)
            out[((size_t)(b * COUT + oc0 + o) * H + oy) * W + ox] =
                fmaxf(acc[j][o] * sc[o] + bi[o], 0.f);
    }
}

// ---------- 2x2 maxpool stride 2 (VALID) ----------
__global__ void k_maxpool(const float* __restrict__ in, float* __restrict__ out,
                          int C, int Hin, int Win, int Hout, int Wout, int total) {
    int idx = blockIdx.x * blockDim.x + threadIdx.x;
    if (idx >= total) return;
    int ox = idx % Wout; int t = idx / Wout;
    int oy = t % Hout; t /= Hout;
    int c = t % C; int b = t / C;
    const float* p = in + ((size_t)(b * C + c) * Hin + 2 * oy) * Win + 2 * ox;
    float m0 = fmaxf(p[0], p[1]);
    float m1 = fmaxf(p[Win], p[Win + 1]);
    out[idx] = fmaxf(m0, m1);
}

// ---------- fused audio attention (both stages) + spatial GAP ----------
__global__ void __launch_bounds__(128) k_audio_attn(
    const float* __restrict__ x,
    const float* __restrict__ wq1, const float* __restrict__ bq1,
    const float* __restrict__ wk1, const float* __restrict__ bk1,
    const float* __restrict__ wv1, const float* __restrict__ bv1,
    const float* __restrict__ wq2, const float* __restrict__ bq2,
    const float* __restrict__ wk2, const float* __restrict__ bk2,
    const float* __restrict__ wv2, const float* __restrict__ bv2,
    float* __restrict__ afeat) {
    int b = blockIdx.x, n = blockIdx.y, stage = blockIdx.z;
    const float* wq = stage ? wq2 : wq1; const float* bq = stage ? bq2 : bq1;
    const float* wk = stage ? wk2 : wk1; const float* bk = stage ? bk2 : bk1;
    const float* wv = stage ? wv2 : wv1; const float* bv = stage ? bv2 : bv1;
    __shared__ float xt[96 * 26];
    __shared__ float sb[96 * 26];
    __shared__ float mx[26], sm[26];
    int tid = threadIdx.x;
    int o = tid;
    float bqv = 0.f, bkv = 0.f, bvv = 0.f;
    const float *wqb = wq, *wkb = wk, *wvb = wv;
    if (o < 96) {
        bqv = bq[n * 96 + o]; bkv = bk[n * 96 + o]; bvv = bv[n * 96 + o];
        wqb = wq + n * 9216 + o; wkb = wk + n * 9216 + o; wvb = wv + n * 9216 + o;
    }
    float accO = 0.f;
    const float* xb = x + (size_t)b * 96 * 234;
    for (int tile = 0; tile < 9; ++tile) {
        int p0 = tile * 26;
        for (int e = tid; e < 96 * 26; e += 128) {
            int c = e / 26, pp = e - c * 26;
            xt[e] = xb[c * 234 + p0 + pp];
        }
        __syncthreads();
        float av[26];
        if (o < 96) {
            float aq[26], ak[26];
            #pragma unroll
            for (int p = 0; p < 26; ++p) { aq[p] = 0.f; ak[p] = 0.f; av[p] = 0.f; }
            for (int c = 0; c < 96; ++c) {
                float wqv = wqb[c * 96], wkv = wkb[c * 96], wvv2 = wvb[c * 96];
                const float* xr = xt + c * 26;
                #pragma unroll
                for (int p = 0; p < 26; ++p) {
                    float xv = xr[p];
                    aq[p] += wqv * xv; ak[p] += wkv * xv; av[p] += wvv2 * xv;
                }
            }
            #pragma unroll
            for (int p = 0; p < 26; ++p)
                sb[o * 26 + p] = (aq[p] + bqv) * (ak[p] + bkv);
        }
        __syncthreads();
        if (tid < 26) {
            float mxv = -1e30f;
            for (int oo = 0; oo < 96; ++oo) mxv = fmaxf(mxv, sb[oo * 26 + tid]);
            float s = 0.f;
            for (int oo = 0; oo < 96; ++oo) s += expf(sb[oo * 26 + tid] - mxv);
            mx[tid] = mxv; sm[tid] = s;
        }
        __syncthreads();
        if (o < 96) {
            #pragma unroll
            for (int p = 0; p < 26; ++p)
                accO += expf(sb[o * 26 + p] - mx[p]) / sm[p] * (av[p] + bvv);
        }
        __syncthreads();
    }
    if (o < 96) afeat[b * 1536 + n * 192 + stage * 96 + o] = accO * (1.f / 234.f);
}

// ---------- global average pool over 234 spatial positions ----------
__global__ void k_gap(const float* __restrict__ x, float* __restrict__ xgap) {
    int b = blockIdx.x; int c = threadIdx.x;
    if (c >= 96) return;
    const float* p = x + (size_t)(b * 96 + c) * 234;
    float s = 0.f;
    for (int i = 0; i < 234; ++i) s += p[i];
    xgap[b * 96 + c] = s * (1.f / 234.f);
}

// ---------- embedding lookup + input-side GRU GEMM ----------
__global__ void k_gi(const int* __restrict__ tokens, const float* __restrict__ emb,
                     const float* __restrict__ wiht, const float* __restrict__ b_ih,
                     float* __restrict__ GI) {
    int bt = blockIdx.x;
    __shared__ float er[200];
    int tok = tokens[bt];
    for (int k = threadIdx.x; k < 200; k += 256) er[k] = emb[(size_t)tok * 200 + k];
    __syncthreads();
    for (int j = threadIdx.x; j < 300; j += 256) {
        float acc = b_ih[j];
        for (int k = 0; k < 200; ++k) acc += wiht[k * 300 + j] * er[k];
        GI[(size_t)bt * 300 + j] = acc;
    }
}

// ---------- one GRU time step ----------
__global__ void __launch_bounds__(320) k_gru_step(const float* __restrict__ GI,
        const float* __restrict__ whht, const float* __restrict__ b_hh,
        float* __restrict__ outs, int t) {
    int b = blockIdx.x; int tid = threadIdx.x;
    __shared__ float hprev[100];
    __shared__ float gI[300], gH[300];
    if (tid < 100) hprev[tid] = (t == 0) ? 0.f : outs[(size_t)(b * kT + t - 1) * 100 + tid];
    __syncthreads();
    if (tid < 300) {
        float acc = b_hh[tid];
        for (int k = 0; k < 100; ++k) acc += whht[k * 300 + tid] * hprev[k];
        gH[tid] = acc;
        gI[tid] = GI[(size_t)(b * kT + t) * 300 + tid];
    }
    __syncthreads();
    if (tid < 100) {
        float r = 1.f / (1.f + expf(-(gI[tid] + gH[tid])));
        float z = 1.f / (1.f + expf(-(gI[100 + tid] + gH[100 + tid])));
        float nn = tanhf(gI[200 + tid] + r * gH[200 + tid]);
        float h2 = (1.f - z) * nn + z * hprev[tid];
        outs[(size_t)(b * kT + t) * 100 + tid] = h2;
    }
}

// ---------- fused text attention (both stages), summed over T in-kernel ----------
__global__ void __launch_bounds__(128) k_text_attn(const float* __restrict__ outs,
    const float* __restrict__ wq1, const float* __restrict__ bq1,
    const float* __restrict__ wk1, const float* __restrict__ bk1,
    const float* __restrict__ wv1, const float* __restrict__ bv1,
    const float* __restrict__ wq2, const float* __restrict__ bq2,
    const float* __restrict__ wk2, const float* __restrict__ bk2,
    const float* __restrict__ wv2, const float* __restrict__ bv2,
    float* __restrict__ tfeat) {
    int b = blockIdx.x, stage = blockIdx.y, n = blockIdx.z;
    const float* wq = stage ? wq2 : wq1; const float* bq = stage ? bq2 : bq1;
    const float* wk = stage ? wk2 : wk1; const float* bk = stage ? bk2 : bk1;
    const float* wv = stage ? wv2 : wv1; const float* bv = stage ? bv2 : bv1;
    int tid = threadIdx.x;
    __shared__ float row[100];
    __shared__ float sb[96];
    __shared__ float red[2];
    float acc = 0.f;
    float bqv = 0.f, bkv = 0.f, bvv = 0.f;
    const float *wqb = wq, *wkb = wk, *wvb = wv;
    if (tid < 96) {
        bqv = bq[n * 96 + tid]; bkv = bk[n * 96 + tid]; bvv = bv[n * 96 + tid];
        wqb = wq + n * 9600 + tid; wkb = wk + n * 9600 + tid; wvb = wv + n * 9600 + tid;
    }
    for (int t = 0; t < kT; ++t) {
        __syncthreads();
        for (int k = tid; k < 100; k += 128) row[k] = outs[(size_t)(b * kT + t) * 100 + k];
        __syncthreads();
        float s = 0.f, vv = 0.f;
        if (tid < 96) {
            float q = bqv, kk = bkv, v_ = bvv;
            for (int c = 0; c < 100; ++c) {
                float xv = row[c];
                q += wqb[c * 96] * xv; kk += wkb[c * 96] * xv; v_ += wvb[c * 96] * xv;
            }
            s = q * kk; vv = v_;
            sb[tid] = s;
        }
        __syncthreads();
        if (tid == 0) {
            float mxv = -1e30f;
            for (int oo = 0; oo < 96; ++oo) mxv = fmaxf(mxv, sb[oo]);
            float smv = 0.f;
            for (int oo = 0; oo < 96; ++oo) smv += expf(sb[oo] - mxv);
            red[0] = mxv; red[1] = smv;
        }
        __syncthreads();
        if (tid < 96) acc += expf(s - red[0]) / red[1] * vv;
    }
    if (tid < 96) tfeat[b * 1536 + stage * 768 + n * 96 + tid] = acc;
}

// ---------- cross-modal gated fusion + final logits ----------
__global__ void __launch_bounds__(128) k_final(const float* __restrict__ xgap,
    const float* __restrict__ outs, const float* __restrict__ afeat,
    const float* __restrict__ tfeat,
    const float* __restrict__ w_fa, const float* __restrict__ b_fa,
    const float* __restrict__ w_ft, const float* __restrict__ b_ft,
    const float* __restrict__ w_e, const float* __restrict__ b_e,
    float* __restrict__ out) {
    int b = blockIdx.x; int tid = threadIdx.x;
    __shared__ float xg[96], hv[100], st[100], sa[96], aat[96], atba[100];
    __shared__ float redm[2], reds[2];
    if (tid < 96) xg[tid] = xgap[b * 96 + tid];
    if (tid < 100) hv[tid] = outs[(size_t)(b * kT + kT - 1) * 100 + tid];
    __syncthreads();
    if (tid < 100) {
        float acc = b_fa[tid];
        const float* wr = w_fa + tid * 96;
        for (int c = 0; c < 96; ++c) acc += wr[c] * xg[c];
        st[tid] = acc;
    }
    if (tid < 96) {
        float acc = b_ft[tid];
        const float* wr = w_ft + tid * 100;
        for (int c = 0; c < 100; ++c) acc += wr[c] * hv[c];
        sa[tid] = acc;
    }
    __syncthreads();
    if (tid == 0) {
        float mxv = -1e30f; for (int i = 0; i < 100; ++i) mxv = fmaxf(mxv, st[i]);
        float s = 0.f; for (int i = 0; i < 100; ++i) s += expf(st[i] - mxv);
        redm[0] = mxv; reds[0] = s;
    }
    if (tid == 1) {
        float mxv = -1e30f; for (int i = 0; i < 96; ++i) mxv = fmaxf(mxv, sa[i]);
        float s = 0.f; for (int i = 0; i < 96; ++i) s += expf(sa[i] - mxv);
        redm[1] = mxv; reds[1] = s;
    }
    __syncthreads();
    if (tid < 100) atba[tid] = expf(st[tid] - redm[0]) / reds[0] * hv[tid];
    if (tid < 96)  aat[tid]  = expf(sa[tid] - redm[1]) / reds[1] * xg[tid];
    __syncthreads();
    float a0 = 0.f, a1 = 0.f, a2 = 0.f, a3 = 0.f;
    for (int col = tid; col < 3268; col += 128) {
        float f;
        if (col < 1536)      f = afeat[b * 1536 + col];
        else if (col < 3072) f = tfeat[b * 1536 + col - 1536];
        else if (col < 3168) f = aat[col - 3072];
        else                 f = atba[col - 3168];
        a0 += w_e[col] * f;            a1 += w_e[3268 + col] * f;
        a2 += w_e[2 * 3268 + col] * f; a3 += w_e[3 * 3268 + col] * f;
    }
    __shared__ float r4[4][128];
    r4[0][tid] = a0; r4[1][tid] = a1; r4[2][tid] = a2; r4[3][tid] = a3;
    __syncthreads();
    if (tid < 4) {
        float s = 0.f;
        for (int i = 0; i < 128; ++i) s += r4[tid][i];
        out[b * 4 + tid] = s + b_e[tid];
    }
}

// =====================================================================
extern "C" void kernel_launch(void* const* d_in, const int* in_sizes, int n_in,
                              void* d_out, int out_size, void* d_ws, size_t ws_size,
                              hipStream_t stream) {
    (void)in_sizes; (void)n_in; (void)out_size; (void)ws_size;
    const float* mfcc_t = (const float*)d_in[0];
    const float* mfcc_f = (const float*)d_in[1];
    const float* mfcc_c = (const float*)d_in[2];
    const int*   tokens = (const int*)d_in[3];
    const float *w1a = (const float*)d_in[5],  *b1a = (const float*)d_in[6],
                *g1a = (const float*)d_in[7],  *be1a = (const float*)d_in[8],
                *m1a = (const float*)d_in[9],  *v1a = (const float*)d_in[10];
    const float *w1b = (const float*)d_in[11], *b1b = (const float*)d_in[12],
                *g1b = (const float*)d_in[13], *be1b = (const float*)d_in[14],
                *m1b = (const float*)d_in[15], *v1b = (const float*)d_in[16];
    const float *w2 = (const float*)d_in[17], *b2 = (const float*)d_in[18],
                *g2 = (const float*)d_in[19], *be2 = (const float*)d_in[20],
                *m2 = (const float*)d_in[21], *v2 = (const float*)d_in[22];
    const float *w3 = (const float*)d_in[23], *b3 = (const float*)d_in[24],
                *g3 = (const float*)d_in[25], *be3 = (const float*)d_in[26],
                *m3 = (const float*)d_in[27], *v3 = (const float*)d_in[28];
    const float *w4 = (const float*)d_in[29], *b4 = (const float*)d_in[30],
                *g4 = (const float*)d_in[31], *be4 = (const float*)d_in[32],
                *m4 = (const float*)d_in[33], *v4 = (const float*)d_in[34];
    const float *wq_a1 = (const float*)d_in[35], *bq_a1 = (const float*)d_in[36],
                *wk_a1 = (const float*)d_in[37], *bk_a1 = (const float*)d_in[38],
                *wv_a1 = (const float*)d_in[39], *bv_a1 = (const float*)d_in[40];
    const float *wq_a2 = (const float*)d_in[41], *bq_a2 = (const float*)d_in[42],
                *wk_a2 = (const float*)d_in[43], *bk_a2 = (const float*)d_in[44],
                *wv_a2 = (const float*)d_in[45], *bv_a2 = (const float*)d_in[46];
    const float *emb  = (const float*)d_in[47];
    const float *w_ih = (const float*)d_in[48], *w_hh = (const float*)d_in[49],
                *b_ih = (const float*)d_in[50], *b_hh = (const float*)d_in[51];
    const float *wq_t1 = (const float*)d_in[52], *bq_t1 = (const float*)d_in[53],
                *wk_t1 = (const float*)d_in[54], *bk_t1 = (const float*)d_in[55],
                *wv_t1 = (const float*)d_in[56], *bv_t1 = (const float*)d_in[57];
    const float *wq_t2 = (const float*)d_in[58], *bq_t2 = (const float*)d_in[59],
                *wk_t2 = (const float*)d_in[60], *bk_t2 = (const float*)d_in[61],
                *wv_t2 = (const float*)d_in[62], *bv_t2 = (const float*)d_in[63];
    const float *w_fa = (const float*)d_in[64], *b_fa = (const float*)d_in[65],
                *w_ft = (const float*)d_in[66], *b_ft = (const float*)d_in[67],
                *w_e  = (const float*)d_in[68], *b_e  = (const float*)d_in[69];

    float* ws = (float*)d_ws;
    const size_t Z0 = 0;                 // 22,091,776 : xa|xb|xc -> c2 -> c3 -> x4
    const size_t Z1 = 22091776ull;       // 11,980,800 : x1 -> p2 -> p3 -> GI
    const size_t OUTS  = 34072576ull;    //    640,000 : conv-wT (early) then GRU outputs
    const size_t AFEAT = 34712576ull;
    const size_t TFEAT = 34909184ull;
    const size_t XGAP  = 35105792ull;
    const size_t WT    = 35118080ull;
    float* XA = ws + Z0;
    float* XB = ws + Z0 + 7827456ull;
    float* XC = ws + Z0 + 14959616ull;
    float* X1 = ws + Z1;
    float* C2 = ws + Z0;  float* P2 = ws + Z1;
    float* C3 = ws + Z0;  float* P3 = ws + Z1;
    float* X4 = ws + Z0;  float* GI = ws + Z1;
    float* outs  = ws + OUTS;
    float* afeat = ws + AFEAT;
    float* tfeat = ws + TFEAT;
    float* xgap  = ws + XGAP;
    float* wqa1t = ws + WT;
    float* wka1t = wqa1t + 73728; float* wva1t = wka1t + 73728;
    float* wqa2t = wva1t + 73728; float* wka2t = wqa2t + 73728; float* wva2t = wka2t + 73728;
    float* wqt1t = wva2t + 73728;
    float* wkt1t = wqt1t + 76800; float* wvt1t = wkt1t + 76800;
    float* wqt2t = wvt1t + 76800; float* wkt2t = wqt2t + 76800; float* wvt2t = wkt2t + 76800;
    float* wiht  = wvt2t + 76800;
    float* whht  = wiht + 60000;
    // conv weight transposes live in the (currently dead) GRU outs region:
    // they are consumed by conv2/3/4, all of which complete before the GRU writes outs.
    float* wT2 = outs;            //  6,912
    float* wT3 = outs + 6912;     // 18,432
    float* wT4 = outs + 25344;    // 55,296  (total 80,640 << 640,000)

    // ----- weight transposes -----
    k_transpose_oc<<<288, 256, 0, stream>>>(wq_a1, wqa1t, 8, 96, 96);
    k_transpose_oc<<<288, 256, 0, stream>>>(wk_a1, wka1t, 8, 96, 96);
    k_transpose_oc<<<288, 256, 0, stream>>>(wv_a1, wva1t, 8, 96, 96);
    k_transpose_oc<<<288, 256, 0, stream>>>(wq_a2, wqa2t, 8, 96, 96);
    k_transpose_oc<<<288, 256, 0, stream>>>(wk_a2, wka2t, 8, 96, 96);
    k_transpose_oc<<<288, 256, 0, stream>>>(wv_a2, wva2t, 8, 96, 96);
    k_transpose_oc<<<300, 256, 0, stream>>>(wq_t1, wqt1t, 8, 96, 100);
    k_transpose_oc<<<300, 256, 0, stream>>>(wk_t1, wkt1t, 8, 96, 100);
    k_transpose_oc<<<300, 256, 0, stream>>>(wv_t1, wvt1t, 8, 96, 100);
    k_transpose_oc<<<300, 256, 0, stream>>>(wq_t2, wqt2t, 8, 96, 100);
    k_transpose_oc<<<300, 256, 0, stream>>>(wk_t2, wkt2t, 8, 96, 100);
    k_transpose_oc<<<300, 256, 0, stream>>>(wv_t2, wvt2t, 8, 96, 100);
    k_transpose_oc<<<235, 256, 0, stream>>>(w_ih, wiht, 1, 300, 200);
    k_transpose_oc<<<118, 256, 0, stream>>>(w_hh, whht, 1, 300, 100);
    k_transpose_convw<<<27, 256, 0, stream>>>(w2, wT2, 24, 32);
    k_transpose_convw<<<72, 256, 0, stream>>>(w3, wT3, 32, 64);
    k_transpose_convw<<<216, 256, 0, stream>>>(w4, wT4, 64, 96);

    // ----- audio CNN stem -----
    k_conv1_bn_relu<<<30576, 256, 0, stream>>>(mfcc_t, w1a, b1a, g1a, be1a, m1a, v1a,
                                               XA, 200, 40, 196, 39, 5, 2, 7827456);
    k_conv1_bn_relu<<<27860, 256, 0, stream>>>(mfcc_f, w1b, b1b, g1b, be1b, m1b, v1b,
                                               XB, 200, 40, 199, 35, 2, 6, 7132160);
    k_conv1_bn_relu<<<27860, 256, 0, stream>>>(mfcc_c, w1b, b1b, g1b, be1b, m1b, v1b,
                                               XC, 200, 40, 199, 35, 2, 6, 7132160);
    k_resize_concat<<<46800, 256, 0, stream>>>(XA, XB, XC, X1, 11980800);
    // conv2: 24->32 @25x156, ROWS=9 (tiles 9,9,7), NPX=6, LDS ~58 KB
    k_conv3x3_tiled<24, 8, 25, 156, 9, 6><<<dim3(128, 3, 4), 256, 0, stream>>>(
        X1, wT2, b2, g2, be2, m2, v2, C2, 32);
    k_maxpool<<<14976, 256, 0, stream>>>(C2, P2, 32, 25, 156, 12, 78, 3833856);
    // conv3: 32->64 @12x78, whole image per block, NPX=4, LDS ~38 KB
    k_conv3x3_tiled<32, 8, 12, 78, 12, 4><<<dim3(128, 1, 8), 256, 0, stream>>>(
        P2, wT3, b3, g3, be3, m3, v3, C3, 64);
    k_maxpool<<<7488, 256, 0, stream>>>(C3, P3, 64, 12, 78, 6, 39, 1916928);
    // conv4: 64->96 @6x39, whole image per block, NPX=1, LDS ~26 KB
    k_conv3x3_tiled<64, 16, 6, 39, 6, 1><<<dim3(128, 1, 12), 256, 0, stream>>>(
        P3, wT4, b4, g4, be4, m4, v4, X4, 96);

    // ----- audio attention + GAP -----
    k_audio_attn<<<dim3(kB, 8, 2), 128, 0, stream>>>(X4,
        wqa1t, bq_a1, wka1t, bk_a1, wva1t, bv_a1,
        wqa2t, bq_a2, wka2t, bk_a2, wva2t, bv_a2, afeat);
    k_gap<<<kB, 128, 0, stream>>>(X4, xgap);

    // ----- text branch -----
    k_gi<<<kB * kT, 256, 0, stream>>>(tokens, emb, wiht, b_ih, GI);
    for (int t = 0; t < kT; ++t)
        k_gru_step<<<kB, 320, 0, stream>>>(GI, whht, b_hh, outs, t);
    k_text_attn<<<dim3(kB, 2, 8), 128, 0, stream>>>(outs,
        wqt1t, bq_t1, wkt1t, bk_t1, wvt1t, bv_t1,
        wqt2t, bq_t2, wkt2t, bk_t2, wvt2t, bv_t2, tfeat);

    // ----- fusion + logits -----
    k_final<<<kB, 128, 0, stream>>>(xgap, outs, afeat, tfeat,
                                    w_fa, b_fa, w_ft, b_ft, w_e, b_e, (float*)d_out);
}

// Round 3
// 1868.620 us; speedup vs baseline: 2.3789x; 1.2930x over previous
//
#include <hip/hip_runtime.h>
#include <math.h>

// ---------------- constants ----------------
static constexpr int kB = 128;
static constexpr int kT = 50;

// ---------- packed transpose [N][O][C] -> [N][C][O], 9 segments, one launch ----------
struct TDesc { const float* src; float* dst; int O; int C; int total; };
struct TPack { TDesc d[9]; };
__global__ void k_transpose_pack(TPack p) {
    TDesc t = p.d[blockIdx.y];
    int idx = blockIdx.x * 256 + threadIdx.x;
    if (idx >= t.total) return;
    int o = idx % t.O; int r = idx / t.O; int c = r % t.C; int n = r / t.C;
    t.dst[idx] = t.src[((size_t)n * t.O + o) * t.C + c];
}

// ---------- conv (Cin=1, Cout=8, VALID) + BN(eval) + ReLU ----------
__global__ void k_conv1_bn_relu(const float* __restrict__ in, const float* __restrict__ w,
                                const float* __restrict__ cb, const float* __restrict__ g,
                                const float* __restrict__ be, const float* __restrict__ m,
                                const float* __restrict__ v, float* __restrict__ out,
                                int Hin, int Win, int Hout, int Wout, int KH, int KW, int total) {
    int idx = blockIdx.x * blockDim.x + threadIdx.x;
    if (idx >= total) return;
    int ox = idx % Wout; int t = idx / Wout;
    int oy = t % Hout; t /= Hout;
    int oc = t % 8; int b = t / 8;
    const float* ip = in + (b * Hin + oy) * Win + ox;
    const float* wp = w + oc * KH * KW;
    float acc = 0.f;
    for (int ky = 0; ky < KH; ++ky)
        for (int kx = 0; kx < KW; ++kx)
            acc += ip[ky * Win + kx] * wp[ky * KW + kx];
    float s = g[oc] * rsqrtf(v[oc] + 1e-5f);
    float bias = (cb[oc] - m[oc]) * s + be[oc];
    out[idx] = fmaxf(acc * s + bias, 0.f);
}

// ---------- half-pixel bilinear resize (no antialias) + channel concat ----------
__global__ void k_resize_concat(const float* __restrict__ xa, const float* __restrict__ xb,
                                const float* __restrict__ xc, float* __restrict__ out, int total) {
    int idx = blockIdx.x * blockDim.x + threadIdx.x;
    if (idx >= total) return;
    int ox = idx % 156; int t = idx / 156;
    int oy = t % 25; t /= 25;
    int ch = t % 24; int b = t / 24;
    int grp = ch >> 3, c = ch & 7;
    const float* src; int Hin, Win;
    if (grp == 0) { src = xa; Hin = 196; Win = 39; }
    else          { src = (grp == 1 ? xb : xc); Hin = 199; Win = 35; }
    float sy = (oy + 0.5f) * ((float)Hin / 25.f) - 0.5f;
    float sx = (ox + 0.5f) * ((float)Win / 156.f) - 0.5f;
    float fy0 = floorf(sy), fx0 = floorf(sx);
    float fy = sy - fy0, fx = sx - fx0;
    int y0 = (int)fy0, x0 = (int)fx0;
    int y0c = min(max(y0, 0), Hin - 1), y1c = min(max(y0 + 1, 0), Hin - 1);
    int x0c = min(max(x0, 0), Win - 1), x1c = min(max(x0 + 1, 0), Win - 1);
    const float* p = src + (size_t)(b * 8 + c) * Hin * Win;
    float v00 = p[y0c * Win + x0c], v01 = p[y0c * Win + x1c];
    float v10 = p[y1c * Win + x0c], v11 = p[y1c * Win + x1c];
    out[idx] = v00 * (1.f - fy) * (1.f - fx) + v01 * (1.f - fy) * fx
             + v10 * fy * (1.f - fx) + v11 * fy * fx;
}

// ---------- LDS-tiled 3x3 conv, pad 1, fused BN(eval) + ReLU ----------
template<int CIN, int CI_T, int H, int W, int ROWS, int NPX>
__global__ void __launch_bounds__(256) k_conv3x3_tiled(
    const float* __restrict__ in, const float* __restrict__ wT,
    const float* __restrict__ cb, const float* __restrict__ g,
    const float* __restrict__ be, const float* __restrict__ m,
    const float* __restrict__ v, float* __restrict__ out, int COUT) {
    constexpr int WP = W + 2;
    constexpr int RP = ROWS + 2;
    constexpr int STAGE = CI_T * RP * WP;
    __shared__ float sx[STAGE];
    __shared__ float sw[CI_T * 9 * 8];
    const int b = blockIdx.x, rt = blockIdx.y, oc0 = blockIdx.z * 8;
    const int row0 = rt * ROWS;
    const int tid = threadIdx.x;

    int off[NPX]; bool val[NPX];
    #pragma unroll
    for (int j = 0; j < NPX; ++j) {
        int px = tid + j * 256;
        int oy = px / W, ox = px - oy * W;
        bool ok = (px < ROWS * W) && (row0 + oy < H);
        val[j] = ok;
        off[j] = ok ? (oy * WP + ox) : 0;
    }

    float acc[NPX][8];
    #pragma unroll
    for (int j = 0; j < NPX; ++j)
        #pragma unroll
        for (int o = 0; o < 8; ++o) acc[j][o] = 0.f;

    for (int c0 = 0; c0 < CIN; c0 += CI_T) {
        __syncthreads();
        for (int e = tid; e < STAGE; e += 256) {
            int ci = e / (RP * WP);
            int rem = e - ci * RP * WP;
            int r = rem / WP;
            int xx = rem - r * WP;
            int iy = row0 - 1 + r;
            int ix = xx - 1;
            float vv = 0.f;
            if (iy >= 0 && iy < H && ix >= 0 && ix < W)
                vv = in[((size_t)(b * CIN + c0 + ci) * H + iy) * W + ix];
            sx[e] = vv;
        }
        for (int e = tid; e < CI_T * 9 * 8; e += 256) {
            int rk = e >> 3;
            int o = e & 7;
            sw[e] = wT[((size_t)c0 * 9 + rk) * COUT + oc0 + o];
        }
        __syncthreads();
        #pragma unroll 1
        for (int cl = 0; cl < CI_T; ++cl) {
            const float* sxc = sx + cl * RP * WP;
            #pragma unroll
            for (int k = 0; k < 9; ++k) {
                const int ky = k / 3, kx = k % 3;
                const float4 wa = *(const float4*)(sw + (cl * 9 + k) * 8);
                const float4 wb = *(const float4*)(sw + (cl * 9 + k) * 8 + 4);
                #pragma unroll
                for (int j = 0; j < NPX; ++j) {
                    float xv = sxc[off[j] + ky * WP + kx];
                    acc[j][0] += xv * wa.x; acc[j][1] += xv * wa.y;
                    acc[j][2] += xv * wa.z; acc[j][3] += xv * wa.w;
                    acc[j][4] += xv * wb.x; acc[j][5] += xv * wb.y;
                    acc[j][6] += xv * wb.z; acc[j][7] += xv * wb.w;
                }
            }
        }
    }
    float sc[8], bi[8];
    #pragma unroll
    for (int o = 0; o < 8; ++o) {
        float s = g[oc0 + o] * rsqrtf(v[oc0 + o] + 1e-5f);
        sc[o] = s; bi[o] = (cb[oc0 + o] - m[oc0 + o]) * s + be[oc0 + o];
    }
    #pragma unroll
    for (int j = 0; j < NPX; ++j) if (val[j]) {
        int px = tid + j * 256;
        int oy = row0 + px / W, ox = px % W;
        #pragma unroll
        for (int o = 0; o < 8; ++o)
            out[((size_t)(b * COUT + oc0 + o) * H + oy) * W + ox] =
                fmaxf(acc[j][o] * sc[o] + bi[o], 0.f);
    }
}

// ---------- 2x2 maxpool stride 2 (VALID) ----------
__global__ void k_maxpool(const float* __restrict__ in, float* __restrict__ out,
                          int C, int Hin, int Win, int Hout, int Wout, int total) {
    int idx = blockIdx.x * blockDim.x + threadIdx.x;
    if (idx >= total) return;
    int ox = idx % Wout; int t = idx / Wout;
    int oy = t % Hout; t /= Hout;
    int c = t % C; int b = t / C;
    const float* p = in + ((size_t)(b * C + c) * Hin + 2 * oy) * Win + 2 * ox;
    float m0 = fmaxf(p[0], p[1]);
    float m1 = fmaxf(p[Win], p[Win + 1]);
    out[idx] = fmaxf(m0, m1);
}

// ---------- fused audio attention (both stages) + spatial GAP ----------
__global__ void __launch_bounds__(128) k_audio_attn(
    const float* __restrict__ x,
    const float* __restrict__ wq1, const float* __restrict__ bq1,
    const float* __restrict__ wk1, const float* __restrict__ bk1,
    const float* __restrict__ wv1, const float* __restrict__ bv1,
    const float* __restrict__ wq2, const float* __restrict__ bq2,
    const float* __restrict__ wk2, const float* __restrict__ bk2,
    const float* __restrict__ wv2, const float* __restrict__ bv2,
    float* __restrict__ afeat) {
    int b = blockIdx.x, n = blockIdx.y, stage = blockIdx.z;
    const float* wq = stage ? wq2 : wq1; const float* bq = stage ? bq2 : bq1;
    const float* wk = stage ? wk2 : wk1; const float* bk = stage ? bk2 : bk1;
    const float* wv = stage ? wv2 : wv1; const float* bv = stage ? bv2 : bv1;
    __shared__ float xt[96 * 26];
    __shared__ float sb[96 * 26];
    __shared__ float mx[26], sm[26];
    int tid = threadIdx.x;
    int o = tid;
    float bqv = 0.f, bkv = 0.f, bvv = 0.f;
    const float *wqb = wq, *wkb = wk, *wvb = wv;
    if (o < 96) {
        bqv = bq[n * 96 + o]; bkv = bk[n * 96 + o]; bvv = bv[n * 96 + o];
        wqb = wq + n * 9216 + o; wkb = wk + n * 9216 + o; wvb = wv + n * 9216 + o;
    }
    float accO = 0.f;
    const float* xb = x + (size_t)b * 96 * 234;
    for (int tile = 0; tile < 9; ++tile) {
        int p0 = tile * 26;
        for (int e = tid; e < 96 * 26; e += 128) {
            int c = e / 26, pp = e - c * 26;
            xt[e] = xb[c * 234 + p0 + pp];
        }
        __syncthreads();
        float av[26];
        if (o < 96) {
            float aq[26], ak[26];
            #pragma unroll
            for (int p = 0; p < 26; ++p) { aq[p] = 0.f; ak[p] = 0.f; av[p] = 0.f; }
            for (int c = 0; c < 96; ++c) {
                float wqv = wqb[c * 96], wkv = wkb[c * 96], wvv2 = wvb[c * 96];
                const float* xr = xt + c * 26;
                #pragma unroll
                for (int p = 0; p < 26; ++p) {
                    float xv = xr[p];
                    aq[p] += wqv * xv; ak[p] += wkv * xv; av[p] += wvv2 * xv;
                }
            }
            #pragma unroll
            for (int p = 0; p < 26; ++p)
                sb[o * 26 + p] = (aq[p] + bqv) * (ak[p] + bkv);
        }
        __syncthreads();
        if (tid < 26) {
            float mxv = -1e30f;
            for (int oo = 0; oo < 96; ++oo) mxv = fmaxf(mxv, sb[oo * 26 + tid]);
            float s = 0.f;
            for (int oo = 0; oo < 96; ++oo) s += expf(sb[oo * 26 + tid] - mxv);
            mx[tid] = mxv; sm[tid] = s;
        }
        __syncthreads();
        if (o < 96) {
            #pragma unroll
            for (int p = 0; p < 26; ++p)
                accO += expf(sb[o * 26 + p] - mx[p]) / sm[p] * (av[p] + bvv);
        }
        __syncthreads();
    }
    if (o < 96) afeat[b * 1536 + n * 192 + stage * 96 + o] = accO * (1.f / 234.f);
}

// ---------- global average pool over 234 spatial positions ----------
__global__ void k_gap(const float* __restrict__ x, float* __restrict__ xgap) {
    int b = blockIdx.x; int c = threadIdx.x;
    if (c >= 96) return;
    const float* p = x + (size_t)(b * 96 + c) * 234;
    float s = 0.f;
    for (int i = 0; i < 234; ++i) s += p[i];
    xgap[b * 96 + c] = s * (1.f / 234.f);
}

// ---------- embedding lookup + input-side GRU GEMM, 8 rows/block ----------
// Uses RAW w_ih layout [300 j][200 k]: thread j float4-loads its own row (L2-hot),
// row activations broadcast from LDS.
__global__ void __launch_bounds__(320) k_gi(const int* __restrict__ tokens,
        const float* __restrict__ emb, const float* __restrict__ w_ih,
        const float* __restrict__ b_ih, float* __restrict__ GI) {
    int r0 = blockIdx.x * 8;
    int tid = threadIdx.x;
    __shared__ float er[8][200];
    for (int e = tid; e < 1600; e += 320) {
        int r = e / 200, c = e - r * 200;
        er[r][c] = emb[(size_t)tokens[r0 + r] * 200 + c];
    }
    __syncthreads();
    if (tid < 300) {
        float acc[8];
        float bv = b_ih[tid];
        #pragma unroll
        for (int r = 0; r < 8; ++r) acc[r] = bv;
        for (int k4 = 0; k4 < 50; ++k4) {
            float4 w4 = *(const float4*)(w_ih + (size_t)tid * 200 + k4 * 4);
            #pragma unroll
            for (int r = 0; r < 8; ++r) {
                float4 x4 = *(const float4*)&er[r][k4 * 4];
                acc[r] += w4.x * x4.x + w4.y * x4.y + w4.z * x4.z + w4.w * x4.w;
            }
        }
        #pragma unroll
        for (int r = 0; r < 8; ++r)
            GI[(size_t)(r0 + r) * 300 + tid] = acc[r];
    }
}

// ---------- whole GRU recurrence in ONE kernel (one block per batch row) ----------
// w_hh row (100 floats) lives in 25 float4 VGPRs per thread, loaded once, reused 50x.
__global__ void __launch_bounds__(320) k_gru_all(const float* __restrict__ GI,
        const float* __restrict__ w_hh, const float* __restrict__ b_hh,
        float* __restrict__ outs) {
    int b = blockIdx.x, tid = threadIdx.x;
    __shared__ float hs[100];
    __shared__ float gH[300];
    float4 wreg[25];
    float bias = 0.f;
    if (tid < 300) {
        bias = b_hh[tid];
        #pragma unroll
        for (int k4 = 0; k4 < 25; ++k4)
            wreg[k4] = *(const float4*)(w_hh + (size_t)tid * 100 + k4 * 4);
    }
    if (tid < 100) hs[tid] = 0.f;
    __syncthreads();
    for (int t = 0; t < kT; ++t) {
        if (tid < 300) {
            float gh = bias;
            #pragma unroll
            for (int k4 = 0; k4 < 25; ++k4) {
                float4 h4 = *(const float4*)&hs[k4 * 4];
                gh += wreg[k4].x * h4.x + wreg[k4].y * h4.y
                    + wreg[k4].z * h4.z + wreg[k4].w * h4.w;
            }
            gH[tid] = gh;
        }
        __syncthreads();   // gH ready; all reads of hs for this step complete
        if (tid < 100) {
            const float* gi = GI + ((size_t)b * kT + t) * 300;
            float r = 1.f / (1.f + expf(-(gi[tid] + gH[tid])));
            float z = 1.f / (1.f + expf(-(gi[100 + tid] + gH[100 + tid])));
            float nn = tanhf(gi[200 + tid] + r * gH[200 + tid]);
            float h2 = (1.f - z) * nn + z * hs[tid];
            hs[tid] = h2;
            outs[((size_t)b * kT + t) * 100 + tid] = h2;
        }
        __syncthreads();   // hs updated before next step's matvec
    }
}

// ---------- fused text attention (both stages), t-tiled, shuffle softmax ----------
// grid (b=128, stage=2, n=8), block 128. RAW weight layout [n][o][c] (c contiguous):
// thread o float4-loads its own weight row; row activations broadcast from LDS b128.
__global__ void __launch_bounds__(128) k_text_attn(const float* __restrict__ outs,
    const float* __restrict__ wq1, const float* __restrict__ bq1,
    const float* __restrict__ wk1, const float* __restrict__ bk1,
    const float* __restrict__ wv1, const float* __restrict__ bv1,
    const float* __restrict__ wq2, const float* __restrict__ bq2,
    const float* __restrict__ wk2, const float* __restrict__ bk2,
    const float* __restrict__ wv2, const float* __restrict__ bv2,
    float* __restrict__ tfeat) {
    int b = blockIdx.x, stage = blockIdx.y, n = blockIdx.z;
    const float* wq = stage ? wq2 : wq1; const float* bq = stage ? bq2 : bq1;
    const float* wk = stage ? wk2 : wk1; const float* bk = stage ? bk2 : bk1;
    const float* wv = stage ? wv2 : wv1; const float* bv = stage ? bv2 : bv1;
    int tid = threadIdx.x;
    bool act = tid < 96;
    int oo = act ? tid : 0;
    const float* wqr = wq + ((size_t)n * 96 + oo) * 100;
    const float* wkr = wk + ((size_t)n * 96 + oo) * 100;
    const float* wvr = wv + ((size_t)n * 96 + oo) * 100;
    float bqv = act ? bq[n * 96 + tid] : 0.f;
    float bkv = act ? bk[n * 96 + tid] : 0.f;
    float bvv = act ? bv[n * 96 + tid] : 0.f;
    __shared__ float rows[10][100];
    __shared__ float wredM[2][10], wredS[2][10];
    float acc = 0.f;
    int wave = tid >> 6, lane = tid & 63;
    for (int tile = 0; tile < 5; ++tile) {
        int t0 = tile * 10;
        __syncthreads();
        for (int e = tid; e < 1000; e += 128) {
            int tt = e / 100, c = e - tt * 100;
            rows[tt][c] = outs[((size_t)b * kT + t0 + tt) * 100 + c];
        }
        __syncthreads();
        float q[10], k[10], v[10];
        #pragma unroll
        for (int tt = 0; tt < 10; ++tt) { q[tt] = bqv; k[tt] = bkv; v[tt] = bvv; }
        for (int c4 = 0; c4 < 25; ++c4) {
            float4 aq = *(const float4*)(wqr + c4 * 4);
            float4 ak = *(const float4*)(wkr + c4 * 4);
            float4 av = *(const float4*)(wvr + c4 * 4);
            #pragma unroll
            for (int tt = 0; tt < 10; ++tt) {
                float4 x4 = *(const float4*)&rows[tt][c4 * 4];
                q[tt] += aq.x * x4.x + aq.y * x4.y + aq.z * x4.z + aq.w * x4.w;
                k[tt] += ak.x * x4.x + ak.y * x4.y + ak.z * x4.z + ak.w * x4.w;
                v[tt] += av.x * x4.x + av.y * x4.y + av.z * x4.z + av.w * x4.w;
            }
        }
        float s[10], e_[10];
        #pragma unroll
        for (int tt = 0; tt < 10; ++tt) s[tt] = act ? q[tt] * k[tt] : -1e30f;
        // per-wave max reduce (6 xor-shuffles), combine 2 waves via LDS
        #pragma unroll
        for (int tt = 0; tt < 10; ++tt) {
            float m = s[tt];
            #pragma unroll
            for (int off = 1; off < 64; off <<= 1) m = fmaxf(m, __shfl_xor(m, off));
            if (lane == 0) wredM[wave][tt] = m;
        }
        __syncthreads();
        #pragma unroll
        for (int tt = 0; tt < 10; ++tt) {
            float mx = fmaxf(wredM[0][tt], wredM[1][tt]);
            e_[tt] = expf(s[tt] - mx);     // inactive lanes: exp(-1e30-mx) -> 0
        }
        #pragma unroll
        for (int tt = 0; tt < 10; ++tt) {
            float sm = e_[tt];
            #pragma unroll
            for (int off = 1; off < 64; off <<= 1) sm += __shfl_xor(sm, off);
            if (lane == 0) wredS[wave][tt] = sm;
        }
        __syncthreads();
        #pragma unroll
        for (int tt = 0; tt < 10; ++tt) {
            float sm = wredS[0][tt] + wredS[1][tt];
            acc += e_[tt] / sm * v[tt];
        }
    }
    if (act) tfeat[b * 1536 + stage * 768 + n * 96 + tid] = acc;
}

// ---------- cross-modal gated fusion + final logits ----------
__global__ void __launch_bounds__(128) k_final(const float* __restrict__ xgap,
    const float* __restrict__ outs, const float* __restrict__ afeat,
    const float* __restrict__ tfeat,
    const float* __restrict__ w_fa, const float* __restrict__ b_fa,
    const float* __restrict__ w_ft, const float* __restrict__ b_ft,
    const float* __restrict__ w_e, const float* __restrict__ b_e,
    float* __restrict__ out) {
    int b = blockIdx.x; int tid = threadIdx.x;
    __shared__ float xg[96], hv[100], st[100], sa[96], aat[96], atba[100];
    __shared__ float redm[2], reds[2];
    if (tid < 96) xg[tid] = xgap[b * 96 + tid];
    if (tid < 100) hv[tid] = outs[(size_t)(b * kT + kT - 1) * 100 + tid];
    __syncthreads();
    if (tid < 100) {
        float acc = b_fa[tid];
        const float* wr = w_fa + tid * 96;
        for (int c = 0; c < 96; ++c) acc += wr[c] * xg[c];
        st[tid] = acc;
    }
    if (tid < 96) {
        float acc = b_ft[tid];
        const float* wr = w_ft + tid * 100;
        for (int c = 0; c < 100; ++c) acc += wr[c] * hv[c];
        sa[tid] = acc;
    }
    __syncthreads();
    if (tid == 0) {
        float mxv = -1e30f; for (int i = 0; i < 100; ++i) mxv = fmaxf(mxv, st[i]);
        float s = 0.f; for (int i = 0; i < 100; ++i) s += expf(st[i] - mxv);
        redm[0] = mxv; reds[0] = s;
    }
    if (tid == 1) {
        float mxv = -1e30f; for (int i = 0; i < 96; ++i) mxv = fmaxf(mxv, sa[i]);
        float s = 0.f; for (int i = 0; i < 96; ++i) s += expf(sa[i] - mxv);
        redm[1] = mxv; reds[1] = s;
    }
    __syncthreads();
    if (tid < 100) atba[tid] = expf(st[tid] - redm[0]) / reds[0] * hv[tid];
    if (tid < 96)  aat[tid]  = expf(sa[tid] - redm[1]) / reds[1] * xg[tid];
    __syncthreads();
    float a0 = 0.f, a1 = 0.f, a2 = 0.f, a3 = 0.f;
    for (int col = tid; col < 3268; col += 128) {
        float f;
        if (col < 1536)      f = afeat[b * 1536 + col];
        else if (col < 3072) f = tfeat[b * 1536 + col - 1536];
        else if (col < 3168) f = aat[col - 3072];
        else                 f = atba[col - 3168];
        a0 += w_e[col] * f;            a1 += w_e[3268 + col] * f;
        a2 += w_e[2 * 3268 + col] * f; a3 += w_e[3 * 3268 + col] * f;
    }
    __shared__ float r4[4][128];
    r4[0][tid] = a0; r4[1][tid] = a1; r4[2][tid] = a2; r4[3][tid] = a3;
    __syncthreads();
    if (tid < 4) {
        float s = 0.f;
        for (int i = 0; i < 128; ++i) s += r4[tid][i];
        out[b * 4 + tid] = s + b_e[tid];
    }
}

// =====================================================================
extern "C" void kernel_launch(void* const* d_in, const int* in_sizes, int n_in,
                              void* d_out, int out_size, void* d_ws, size_t ws_size,
                              hipStream_t stream) {
    (void)in_sizes; (void)n_in; (void)out_size; (void)ws_size;
    const float* mfcc_t = (const float*)d_in[0];
    const float* mfcc_f = (const float*)d_in[1];
    const float* mfcc_c = (const float*)d_in[2];
    const int*   tokens = (const int*)d_in[3];
    const float *w1a = (const float*)d_in[5],  *b1a = (const float*)d_in[6],
                *g1a = (const float*)d_in[7],  *be1a = (const float*)d_in[8],
                *m1a = (const float*)d_in[9],  *v1a = (const float*)d_in[10];
    const float *w1b = (const float*)d_in[11], *b1b = (const float*)d_in[12],
                *g1b = (const float*)d_in[13], *be1b = (const float*)d_in[14],
                *m1b = (const float*)d_in[15], *v1b = (const float*)d_in[16];
    const float *w2 = (const float*)d_in[17], *b2 = (const float*)d_in[18],
                *g2 = (const float*)d_in[19], *be2 = (const float*)d_in[20],
                *m2 = (const float*)d_in[21], *v2 = (const float*)d_in[22];
    const float *w3 = (const float*)d_in[23], *b3 = (const float*)d_in[24],
                *g3 = (const float*)d_in[25], *be3 = (const float*)d_in[26],
                *m3 = (const float*)d_in[27], *v3 = (const float*)d_in[28];
    const float *w4 = (const float*)d_in[29], *b4 = (const float*)d_in[30],
                *g4 = (const float*)d_in[31], *be4 = (const float*)d_in[32],
                *m4 = (const float*)d_in[33], *v4 = (const float*)d_in[34];
    const float *wq_a1 = (const float*)d_in[35], *bq_a1 = (const float*)d_in[36],
                *wk_a1 = (const float*)d_in[37], *bk_a1 = (const float*)d_in[38],
                *wv_a1 = (const float*)d_in[39], *bv_a1 = (const float*)d_in[40];
    const float *wq_a2 = (const float*)d_in[41], *bq_a2 = (const float*)d_in[42],
                *wk_a2 = (const float*)d_in[43], *bk_a2 = (const float*)d_in[44],
                *wv_a2 = (const float*)d_in[45], *bv_a2 = (const float*)d_in[46];
    const float *emb  = (const float*)d_in[47];
    const float *w_ih = (const float*)d_in[48], *w_hh = (const float*)d_in[49],
                *b_ih = (const float*)d_in[50], *b_hh = (const float*)d_in[51];
    const float *wq_t1 = (const float*)d_in[52], *bq_t1 = (const float*)d_in[53],
                *wk_t1 = (const float*)d_in[54], *bk_t1 = (const float*)d_in[55],
                *wv_t1 = (const float*)d_in[56], *bv_t1 = (const float*)d_in[57];
    const float *wq_t2 = (const float*)d_in[58], *bq_t2 = (const float*)d_in[59],
                *wk_t2 = (const float*)d_in[60], *bk_t2 = (const float*)d_in[61],
                *wv_t2 = (const float*)d_in[62], *bv_t2 = (const float*)d_in[63];
    const float *w_fa = (const float*)d_in[64], *b_fa = (const float*)d_in[65],
                *w_ft = (const float*)d_in[66], *b_ft = (const float*)d_in[67],
                *w_e  = (const float*)d_in[68], *b_e  = (const float*)d_in[69];

    float* ws = (float*)d_ws;
    const size_t Z0 = 0;                 // xa|xb|xc -> c2 -> c3 -> x4
    const size_t Z1 = 22091776ull;       // x1 -> p2 -> p3 -> GI
    const size_t OUTS  = 34072576ull;    // conv-wT (early) then GRU outputs
    const size_t AFEAT = 34712576ull;
    const size_t TFEAT = 34909184ull;
    const size_t XGAP  = 35105792ull;
    const size_t WT    = 35118080ull;
    float* XA = ws + Z0;
    float* XB = ws + Z0 + 7827456ull;
    float* XC = ws + Z0 + 14959616ull;
    float* X1 = ws + Z1;
    float* C2 = ws + Z0;  float* P2 = ws + Z1;
    float* C3 = ws + Z0;  float* P3 = ws + Z1;
    float* X4 = ws + Z0;  float* GI = ws + Z1;
    float* outs  = ws + OUTS;
    float* afeat = ws + AFEAT;
    float* tfeat = ws + TFEAT;
    float* xgap  = ws + XGAP;
    float* wqa1t = ws + WT;
    float* wka1t = wqa1t + 73728; float* wva1t = wka1t + 73728;
    float* wqa2t = wva1t + 73728; float* wka2t = wqa2t + 73728; float* wva2t = wka2t + 73728;
    // conv weight transposes parked in the (still dead) GRU outs region:
    // consumed by conv2/3/4, which complete before k_gru_all writes outs.
    float* wT2 = outs;            //  6,912
    float* wT3 = outs + 6912;     // 18,432
    float* wT4 = outs + 25344;    // 55,296

    // ----- all weight transposes in ONE launch -----
    TPack tp;
    tp.d[0] = {wq_a1, wqa1t, 96, 96, 73728};
    tp.d[1] = {wk_a1, wka1t, 96, 96, 73728};
    tp.d[2] = {wv_a1, wva1t, 96, 96, 73728};
    tp.d[3] = {wq_a2, wqa2t, 96, 96, 73728};
    tp.d[4] = {wk_a2, wka2t, 96, 96, 73728};
    tp.d[5] = {wv_a2, wva2t, 96, 96, 73728};
    tp.d[6] = {w2, wT2, 32, 216, 6912};
    tp.d[7] = {w3, wT3, 64, 288, 18432};
    tp.d[8] = {w4, wT4, 96, 576, 55296};
    k_transpose_pack<<<dim3(288, 9), 256, 0, stream>>>(tp);

    // ----- audio CNN stem -----
    k_conv1_bn_relu<<<30576, 256, 0, stream>>>(mfcc_t, w1a, b1a, g1a, be1a, m1a, v1a,
                                               XA, 200, 40, 196, 39, 5, 2, 7827456);
    k_conv1_bn_relu<<<27860, 256, 0, stream>>>(mfcc_f, w1b, b1b, g1b, be1b, m1b, v1b,
                                               XB, 200, 40, 199, 35, 2, 6, 7132160);
    k_conv1_bn_relu<<<27860, 256, 0, stream>>>(mfcc_c, w1b, b1b, g1b, be1b, m1b, v1b,
                                               XC, 200, 40, 199, 35, 2, 6, 7132160);
    k_resize_concat<<<46800, 256, 0, stream>>>(XA, XB, XC, X1, 11980800);
    k_conv3x3_tiled<24, 8, 25, 156, 9, 6><<<dim3(128, 3, 4), 256, 0, stream>>>(
        X1, wT2, b2, g2, be2, m2, v2, C2, 32);
    k_maxpool<<<14976, 256, 0, stream>>>(C2, P2, 32, 25, 156, 12, 78, 3833856);
    k_conv3x3_tiled<32, 8, 12, 78, 12, 4><<<dim3(128, 1, 8), 256, 0, stream>>>(
        P2, wT3, b3, g3, be3, m3, v3, C3, 64);
    k_maxpool<<<7488, 256, 0, stream>>>(C3, P3, 64, 12, 78, 6, 39, 1916928);
    k_conv3x3_tiled<64, 16, 6, 39, 6, 1><<<dim3(128, 1, 12), 256, 0, stream>>>(
        P3, wT4, b4, g4, be4, m4, v4, X4, 96);

    // ----- audio attention + GAP -----
    k_audio_attn<<<dim3(kB, 8, 2), 128, 0, stream>>>(X4,
        wqa1t, bq_a1, wka1t, bk_a1, wva1t, bv_a1,
        wqa2t, bq_a2, wka2t, bk_a2, wva2t, bv_a2, afeat);
    k_gap<<<kB, 128, 0, stream>>>(X4, xgap);

    // ----- text branch: GI (raw w_ih), single-kernel GRU (raw w_hh), fused attn -----
    k_gi<<<kB * kT / 8, 320, 0, stream>>>(tokens, emb, w_ih, b_ih, GI);
    k_gru_all<<<kB, 320, 0, stream>>>(GI, w_hh, b_hh, outs);
    k_text_attn<<<dim3(kB, 2, 8), 128, 0, stream>>>(outs,
        wq_t1, bq_t1, wk_t1, bk_t1, wv_t1, bv_t1,
        wq_t2, bq_t2, wk_t2, bk_t2, wv_t2, bv_t2, tfeat);

    // ----- fusion + logits -----
    k_final<<<kB, 128, 0, stream>>>(xgap, outs, afeat, tfeat,
                                    w_fa, b_fa, w_ft, b_ft, w_e, b_e, (float*)d_out);
}

// Round 4
// 1856.782 us; speedup vs baseline: 2.3941x; 1.0064x over previous
//
#include <hip/hip_runtime.h>
#include <math.h>

// ---------------- constants ----------------
static constexpr int kB = 128;
static constexpr int kT = 50;

// ---------- packed transpose [N][O][C] -> [N][C][O], 9 segments, one launch ----------
struct TDesc { const float* src; float* dst; int O; int C; int total; };
struct TPack { TDesc d[9]; };
__global__ void k_transpose_pack(TPack p) {
    TDesc t = p.d[blockIdx.y];
    int idx = blockIdx.x * 256 + threadIdx.x;
    if (idx >= t.total) return;
    int o = idx % t.O; int r = idx / t.O; int c = r % t.C; int n = r / t.C;
    t.dst[idx] = t.src[((size_t)n * t.O + o) * t.C + c];
}

// ---------- fused stem: conv1{a,b,b} + BN + ReLU + bilinear resize + concat ----------
// out: X1 [128,24,25,156]. Taps are BN+ReLU'd BEFORE bilinear mix (matches ref order).
__global__ void k_stem(const float* __restrict__ mt, const float* __restrict__ mf,
                       const float* __restrict__ mc,
                       const float* __restrict__ w1a, const float* __restrict__ b1a,
                       const float* __restrict__ g1a, const float* __restrict__ be1a,
                       const float* __restrict__ m1a, const float* __restrict__ v1a,
                       const float* __restrict__ w1b, const float* __restrict__ b1b,
                       const float* __restrict__ g1b, const float* __restrict__ be1b,
                       const float* __restrict__ m1b, const float* __restrict__ v1b,
                       float* __restrict__ out, int total) {
    int idx = blockIdx.x * blockDim.x + threadIdx.x;
    if (idx >= total) return;
    int ox = idx % 156; int t = idx / 156;
    int oy = t % 25; t /= 25;
    int ch = t % 24; int b = t / 24;
    int grp = ch >> 3, c = ch & 7;
    const float* src; int Hc, Wc;
    const float *wb, *cb, *g, *be, *m, *v;
    if (grp == 0) { src = mt; Hc = 196; Wc = 39; wb = w1a + c * 10;
                    cb = b1a; g = g1a; be = be1a; m = m1a; v = v1a; }
    else          { src = (grp == 1 ? mf : mc); Hc = 199; Wc = 35; wb = w1b + c * 12;
                    cb = b1b; g = g1b; be = be1b; m = m1b; v = v1b; }
    float s = g[c] * rsqrtf(v[c] + 1e-5f);
    float bias = (cb[c] - m[c]) * s + be[c];
    float sy = (oy + 0.5f) * ((float)Hc / 25.f) - 0.5f;
    float sx = (ox + 0.5f) * ((float)Wc / 156.f) - 0.5f;
    float fy0 = floorf(sy), fx0 = floorf(sx);
    float fy = sy - fy0, fx = sx - fx0;
    int y0 = (int)fy0, x0 = (int)fx0;
    int y0c = min(max(y0, 0), Hc - 1), y1c = min(max(y0 + 1, 0), Hc - 1);
    int x0c = min(max(x0, 0), Wc - 1), x1c = min(max(x0 + 1, 0), Wc - 1);
    const float* p = src + (size_t)b * 8000;   // 200*40
    float t00 = 0.f, t01 = 0.f, t10 = 0.f, t11 = 0.f;
    if (grp == 0) {
        #pragma unroll
        for (int ky = 0; ky < 5; ++ky)
            #pragma unroll
            for (int kx = 0; kx < 2; ++kx) {
                float wv = wb[ky * 2 + kx];
                t00 += p[(y0c + ky) * 40 + x0c + kx] * wv;
                t01 += p[(y0c + ky) * 40 + x1c + kx] * wv;
                t10 += p[(y1c + ky) * 40 + x0c + kx] * wv;
                t11 += p[(y1c + ky) * 40 + x1c + kx] * wv;
            }
    } else {
        #pragma unroll
        for (int ky = 0; ky < 2; ++ky)
            #pragma unroll
            for (int kx = 0; kx < 6; ++kx) {
                float wv = wb[ky * 6 + kx];
                t00 += p[(y0c + ky) * 40 + x0c + kx] * wv;
                t01 += p[(y0c + ky) * 40 + x1c + kx] * wv;
                t10 += p[(y1c + ky) * 40 + x0c + kx] * wv;
                t11 += p[(y1c + ky) * 40 + x1c + kx] * wv;
            }
    }
    float r00 = fmaxf(t00 * s + bias, 0.f), r01 = fmaxf(t01 * s + bias, 0.f);
    float r10 = fmaxf(t10 * s + bias, 0.f), r11 = fmaxf(t11 * s + bias, 0.f);
    out[idx] = r00 * (1.f - fy) * (1.f - fx) + r01 * (1.f - fy) * fx
             + r10 * fy * (1.f - fx) + r11 * fy * fx;
}

// ---------- LDS-tiled 3x3 conv, pad 1, fused BN(eval) + ReLU ----------
template<int CIN, int CI_T, int H, int W, int ROWS, int NPX>
__global__ void __launch_bounds__(256) k_conv3x3_tiled(
    const float* __restrict__ in, const float* __restrict__ wT,
    const float* __restrict__ cb, const float* __restrict__ g,
    const float* __restrict__ be, const float* __restrict__ m,
    const float* __restrict__ v, float* __restrict__ out, int COUT) {
    constexpr int WP = W + 2;
    constexpr int RP = ROWS + 2;
    constexpr int STAGE = CI_T * RP * WP;
    __shared__ float sx[STAGE];
    __shared__ float sw[CI_T * 9 * 8];
    const int b = blockIdx.x, rt = blockIdx.y, oc0 = blockIdx.z * 8;
    const int row0 = rt * ROWS;
    const int tid = threadIdx.x;

    int off[NPX]; bool val[NPX];
    #pragma unroll
    for (int j = 0; j < NPX; ++j) {
        int px = tid + j * 256;
        int oy = px / W, ox = px - oy * W;
        bool ok = (px < ROWS * W) && (row0 + oy < H);
        val[j] = ok;
        off[j] = ok ? (oy * WP + ox) : 0;
    }

    float acc[NPX][8];
    #pragma unroll
    for (int j = 0; j < NPX; ++j)
        #pragma unroll
        for (int o = 0; o < 8; ++o) acc[j][o] = 0.f;

    for (int c0 = 0; c0 < CIN; c0 += CI_T) {
        __syncthreads();
        for (int e = tid; e < STAGE; e += 256) {
            int ci = e / (RP * WP);
            int rem = e - ci * RP * WP;
            int r = rem / WP;
            int xx = rem - r * WP;
            int iy = row0 - 1 + r;
            int ix = xx - 1;
            float vv = 0.f;
            if (iy >= 0 && iy < H && ix >= 0 && ix < W)
                vv = in[((size_t)(b * CIN + c0 + ci) * H + iy) * W + ix];
            sx[e] = vv;
        }
        for (int e = tid; e < CI_T * 9 * 8; e += 256) {
            int rk = e >> 3;
            int o = e & 7;
            sw[e] = wT[((size_t)c0 * 9 + rk) * COUT + oc0 + o];
        }
        __syncthreads();
        #pragma unroll 1
        for (int cl = 0; cl < CI_T; ++cl) {
            const float* sxc = sx + cl * RP * WP;
            #pragma unroll
            for (int k = 0; k < 9; ++k) {
                const int ky = k / 3, kx = k % 3;
                const float4 wa = *(const float4*)(sw + (cl * 9 + k) * 8);
                const float4 wb = *(const float4*)(sw + (cl * 9 + k) * 8 + 4);
                #pragma unroll
                for (int j = 0; j < NPX; ++j) {
                    float xv = sxc[off[j] + ky * WP + kx];
                    acc[j][0] += xv * wa.x; acc[j][1] += xv * wa.y;
                    acc[j][2] += xv * wa.z; acc[j][3] += xv * wa.w;
                    acc[j][4] += xv * wb.x; acc[j][5] += xv * wb.y;
                    acc[j][6] += xv * wb.z; acc[j][7] += xv * wb.w;
                }
            }
        }
    }
    float sc[8], bi[8];
    #pragma unroll
    for (int o = 0; o < 8; ++o) {
        float s = g[oc0 + o] * rsqrtf(v[oc0 + o] + 1e-5f);
        sc[o] = s; bi[o] = (cb[oc0 + o] - m[oc0 + o]) * s + be[oc0 + o];
    }
    #pragma unroll
    for (int j = 0; j < NPX; ++j) if (val[j]) {
        int px = tid + j * 256;
        int oy = row0 + px / W, ox = px % W;
        #pragma unroll
        for (int o = 0; o < 8; ++o)
            out[((size_t)(b * COUT + oc0 + o) * H + oy) * W + ox] =
                fmaxf(acc[j][o] * sc[o] + bi[o], 0.f);
    }
}

// ---------- 2x2 maxpool stride 2 (VALID) ----------
__global__ void k_maxpool(const float* __restrict__ in, float* __restrict__ out,
                          int C, int Hin, int Win, int Hout, int Wout, int total) {
    int idx = blockIdx.x * blockDim.x + threadIdx.x;
    if (idx >= total) return;
    int ox = idx % Wout; int t = idx / Wout;
    int oy = t % Hout; t /= Hout;
    int c = t % C; int b = t / C;
    const float* p = in + ((size_t)(b * C + c) * Hin + 2 * oy) * Win + 2 * ox;
    float m0 = fmaxf(p[0], p[1]);
    float m1 = fmaxf(p[Win], p[Win + 1]);
    out[idx] = fmaxf(m0, m1);
}

// ---------- fused audio attention (both stages) + spatial GAP, shuffle softmax ----------
// x: [128,96,234]. grid (b=128, n=8, stage=2), block 128 (96 active).
// xt row stride 28 (112 B, 16B-aligned) -> ds_read_b128. No score matrix in LDS:
// softmax over o via 6-step wave shuffles + 2-entry cross-wave LDS combine.
// (n==0,stage==0) blocks also produce xgap (GAP over positions).
__global__ void __launch_bounds__(128) k_audio_attn(
    const float* __restrict__ x,
    const float* __restrict__ wq1, const float* __restrict__ bq1,
    const float* __restrict__ wk1, const float* __restrict__ bk1,
    const float* __restrict__ wv1, const float* __restrict__ bv1,
    const float* __restrict__ wq2, const float* __restrict__ bq2,
    const float* __restrict__ wk2, const float* __restrict__ bk2,
    const float* __restrict__ wv2, const float* __restrict__ bv2,
    float* __restrict__ afeat, float* __restrict__ xgap) {
    int b = blockIdx.x, n = blockIdx.y, stage = blockIdx.z;
    const float* wq = stage ? wq2 : wq1; const float* bq = stage ? bq2 : bq1;
    const float* wk = stage ? wk2 : wk1; const float* bk = stage ? bk2 : bk1;
    const float* wv = stage ? wv2 : wv1; const float* bv = stage ? bv2 : bv1;
    __shared__ float xt[96 * 28];
    __shared__ float wmax[2][26], wsum[2][26];
    int tid = threadIdx.x;
    bool act = tid < 96;
    int o = act ? tid : 0;
    int wave = tid >> 6, lane = tid & 63;
    float bqv = act ? bq[n * 96 + tid] : 0.f;
    float bkv = act ? bk[n * 96 + tid] : 0.f;
    float bvv = act ? bv[n * 96 + tid] : 0.f;
    const float* wqb = wq + n * 9216 + o;   // [c][o] layout, access wqb[c*96]
    const float* wkb = wk + n * 9216 + o;
    const float* wvb = wv + n * 9216 + o;
    const bool do_gap = (n == 0 && stage == 0);
    float accO = 0.f, xsum = 0.f;
    const float* xb = x + (size_t)b * 96 * 234;
    for (int tile = 0; tile < 9; ++tile) {
        int p0 = tile * 26;
        __syncthreads();
        for (int e = tid; e < 2496; e += 128) {
            int c = e / 26, pp = e - c * 26;
            xt[c * 28 + pp] = xb[c * 234 + p0 + pp];
        }
        __syncthreads();
        if (do_gap && act) {
            const float* xr = xt + o * 28;
            #pragma unroll
            for (int p = 0; p < 26; ++p) xsum += xr[p];
        }
        float aq[26], ak[26], av[26];
        #pragma unroll
        for (int p = 0; p < 26; ++p) { aq[p] = bqv; ak[p] = bkv; av[p] = bvv; }
        #pragma unroll 2
        for (int c = 0; c < 96; ++c) {
            float wqv = wqb[c * 96], wkv = wkb[c * 96], wvv = wvb[c * 96];
            const float* xr = xt + c * 28;
            #pragma unroll
            for (int q4 = 0; q4 < 7; ++q4) {
                float4 xq = *(const float4*)(xr + q4 * 4);
                #pragma unroll
                for (int j = 0; j < 4; ++j) {
                    int p = q4 * 4 + j;
                    if (p < 26) {
                        float xvv = (j == 0) ? xq.x : (j == 1) ? xq.y : (j == 2) ? xq.z : xq.w;
                        aq[p] += wqv * xvv; ak[p] += wkv * xvv; av[p] += wvv * xvv;
                    }
                }
            }
        }
        float s_[26], e_[26];
        #pragma unroll
        for (int p = 0; p < 26; ++p) s_[p] = act ? aq[p] * ak[p] : -1e30f;
        #pragma unroll
        for (int p = 0; p < 26; ++p) {
            float m_ = s_[p];
            #pragma unroll
            for (int off = 1; off < 64; off <<= 1) m_ = fmaxf(m_, __shfl_xor(m_, off));
            if (lane == 0) wmax[wave][p] = m_;
        }
        __syncthreads();
        #pragma unroll
        for (int p = 0; p < 26; ++p) {
            float mx = fmaxf(wmax[0][p], wmax[1][p]);
            e_[p] = __expf(s_[p] - mx);
        }
        #pragma unroll
        for (int p = 0; p < 26; ++p) {
            float sm_ = e_[p];
            #pragma unroll
            for (int off = 1; off < 64; off <<= 1) sm_ += __shfl_xor(sm_, off);
            if (lane == 0) wsum[wave][p] = sm_;
        }
        __syncthreads();
        #pragma unroll
        for (int p = 0; p < 26; ++p) {
            float sm = wsum[0][p] + wsum[1][p];
            accO += e_[p] / sm * av[p];
        }
    }
    if (act) afeat[b * 1536 + n * 192 + stage * 96 + tid] = accO * (1.f / 234.f);
    if (do_gap && act) xgap[b * 96 + tid] = xsum * (1.f / 234.f);
}

// ---------- embedding lookup + input-side GRU GEMM, 8 rows/block ----------
__global__ void __launch_bounds__(320) k_gi(const int* __restrict__ tokens,
        const float* __restrict__ emb, const float* __restrict__ w_ih,
        const float* __restrict__ b_ih, float* __restrict__ GI) {
    int r0 = blockIdx.x * 8;
    int tid = threadIdx.x;
    __shared__ float er[8][200];
    for (int e = tid; e < 1600; e += 320) {
        int r = e / 200, c = e - r * 200;
        er[r][c] = emb[(size_t)tokens[r0 + r] * 200 + c];
    }
    __syncthreads();
    if (tid < 300) {
        float acc[8];
        float bv = b_ih[tid];
        #pragma unroll
        for (int r = 0; r < 8; ++r) acc[r] = bv;
        for (int k4 = 0; k4 < 50; ++k4) {
            float4 w4 = *(const float4*)(w_ih + (size_t)tid * 200 + k4 * 4);
            #pragma unroll
            for (int r = 0; r < 8; ++r) {
                float4 x4 = *(const float4*)&er[r][k4 * 4];
                acc[r] += w4.x * x4.x + w4.y * x4.y + w4.z * x4.z + w4.w * x4.w;
            }
        }
        #pragma unroll
        for (int r = 0; r < 8; ++r)
            GI[(size_t)(r0 + r) * 300 + tid] = acc[r];
    }
}

// ---------- whole GRU recurrence in ONE kernel (one block per batch row) ----------
__global__ void __launch_bounds__(320) k_gru_all(const float* __restrict__ GI,
        const float* __restrict__ w_hh, const float* __restrict__ b_hh,
        float* __restrict__ outs) {
    int b = blockIdx.x, tid = threadIdx.x;
    __shared__ float hs[100];
    __shared__ float gH[300];
    float4 wreg[25];
    float bias = 0.f;
    if (tid < 300) {
        bias = b_hh[tid];
        #pragma unroll
        for (int k4 = 0; k4 < 25; ++k4)
            wreg[k4] = *(const float4*)(w_hh + (size_t)tid * 100 + k4 * 4);
    }
    if (tid < 100) hs[tid] = 0.f;
    __syncthreads();
    for (int t = 0; t < kT; ++t) {
        if (tid < 300) {
            float gh = bias;
            #pragma unroll
            for (int k4 = 0; k4 < 25; ++k4) {
                float4 h4 = *(const float4*)&hs[k4 * 4];
                gh += wreg[k4].x * h4.x + wreg[k4].y * h4.y
                    + wreg[k4].z * h4.z + wreg[k4].w * h4.w;
            }
            gH[tid] = gh;
        }
        __syncthreads();
        if (tid < 100) {
            const float* gi = GI + ((size_t)b * kT + t) * 300;
            float r = 1.f / (1.f + expf(-(gi[tid] + gH[tid])));
            float z = 1.f / (1.f + expf(-(gi[100 + tid] + gH[100 + tid])));
            float nn = tanhf(gi[200 + tid] + r * gH[200 + tid]);
            float h2 = (1.f - z) * nn + z * hs[tid];
            hs[tid] = h2;
            outs[((size_t)b * kT + t) * 100 + tid] = h2;
        }
        __syncthreads();
    }
}

// ---------- fused text attention (both stages), t-tiled, shuffle softmax ----------
__global__ void __launch_bounds__(128) k_text_attn(const float* __restrict__ outs,
    const float* __restrict__ wq1, const float* __restrict__ bq1,
    const float* __restrict__ wk1, const float* __restrict__ bk1,
    const float* __restrict__ wv1, const float* __restrict__ bv1,
    const float* __restrict__ wq2, const float* __restrict__ bq2,
    const float* __restrict__ wk2, const float* __restrict__ bk2,
    const float* __restrict__ wv2, const float* __restrict__ bv2,
    float* __restrict__ tfeat) {
    int b = blockIdx.x, stage = blockIdx.y, n = blockIdx.z;
    const float* wq = stage ? wq2 : wq1; const float* bq = stage ? bq2 : bq1;
    const float* wk = stage ? wk2 : wk1; const float* bk = stage ? bk2 : bk1;
    const float* wv = stage ? wv2 : wv1; const float* bv = stage ? bv2 : bv1;
    int tid = threadIdx.x;
    bool act = tid < 96;
    int oo = act ? tid : 0;
    const float* wqr = wq + ((size_t)n * 96 + oo) * 100;
    const float* wkr = wk + ((size_t)n * 96 + oo) * 100;
    const float* wvr = wv + ((size_t)n * 96 + oo) * 100;
    float bqv = act ? bq[n * 96 + tid] : 0.f;
    float bkv = act ? bk[n * 96 + tid] : 0.f;
    float bvv = act ? bv[n * 96 + tid] : 0.f;
    __shared__ float rows[10][100];
    __shared__ float wredM[2][10], wredS[2][10];
    float acc = 0.f;
    int wave = tid >> 6, lane = tid & 63;
    for (int tile = 0; tile < 5; ++tile) {
        int t0 = tile * 10;
        __syncthreads();
        for (int e = tid; e < 1000; e += 128) {
            int tt = e / 100, c = e - tt * 100;
            rows[tt][c] = outs[((size_t)b * kT + t0 + tt) * 100 + c];
        }
        __syncthreads();
        float q[10], k[10], v[10];
        #pragma unroll
        for (int tt = 0; tt < 10; ++tt) { q[tt] = bqv; k[tt] = bkv; v[tt] = bvv; }
        for (int c4 = 0; c4 < 25; ++c4) {
            float4 aq = *(const float4*)(wqr + c4 * 4);
            float4 ak = *(const float4*)(wkr + c4 * 4);
            float4 av = *(const float4*)(wvr + c4 * 4);
            #pragma unroll
            for (int tt = 0; tt < 10; ++tt) {
                float4 x4 = *(const float4*)&rows[tt][c4 * 4];
                q[tt] += aq.x * x4.x + aq.y * x4.y + aq.z * x4.z + aq.w * x4.w;
                k[tt] += ak.x * x4.x + ak.y * x4.y + ak.z * x4.z + ak.w * x4.w;
                v[tt] += av.x * x4.x + av.y * x4.y + av.z * x4.z + av.w * x4.w;
            }
        }
        float s[10], e_[10];
        #pragma unroll
        for (int tt = 0; tt < 10; ++tt) s[tt] = act ? q[tt] * k[tt] : -1e30f;
        #pragma unroll
        for (int tt = 0; tt < 10; ++tt) {
            float m = s[tt];
            #pragma unroll
            for (int off = 1; off < 64; off <<= 1) m = fmaxf(m, __shfl_xor(m, off));
            if (lane == 0) wredM[wave][tt] = m;
        }
        __syncthreads();
        #pragma unroll
        for (int tt = 0; tt < 10; ++tt) {
            float mx = fmaxf(wredM[0][tt], wredM[1][tt]);
            e_[tt] = expf(s[tt] - mx);
        }
        #pragma unroll
        for (int tt = 0; tt < 10; ++tt) {
            float sm = e_[tt];
            #pragma unroll
            for (int off = 1; off < 64; off <<= 1) sm += __shfl_xor(sm, off);
            if (lane == 0) wredS[wave][tt] = sm;
        }
        __syncthreads();
        #pragma unroll
        for (int tt = 0; tt < 10; ++tt) {
            float sm = wredS[0][tt] + wredS[1][tt];
            acc += e_[tt] / sm * v[tt];
        }
    }
    if (act) tfeat[b * 1536 + stage * 768 + n * 96 + tid] = acc;
}

// ---------- cross-modal gated fusion + final logits ----------
__global__ void __launch_bounds__(128) k_final(const float* __restrict__ xgap,
    const float* __restrict__ outs, const float* __restrict__ afeat,
    const float* __restrict__ tfeat,
    const float* __restrict__ w_fa, const float* __restrict__ b_fa,
    const float* __restrict__ w_ft, const float* __restrict__ b_ft,
    const float* __restrict__ w_e, const float* __restrict__ b_e,
    float* __restrict__ out) {
    int b = blockIdx.x; int tid = threadIdx.x;
    __shared__ float xg[96], hv[100], st[100], sa[96], aat[96], atba[100];
    __shared__ float redm[2], reds[2];
    if (tid < 96) xg[tid] = xgap[b * 96 + tid];
    if (tid < 100) hv[tid] = outs[(size_t)(b * kT + kT - 1) * 100 + tid];
    __syncthreads();
    if (tid < 100) {
        float acc = b_fa[tid];
        const float* wr = w_fa + tid * 96;
        for (int c = 0; c < 96; ++c) acc += wr[c] * xg[c];
        st[tid] = acc;
    }
    if (tid < 96) {
        float acc = b_ft[tid];
        const float* wr = w_ft + tid * 100;
        for (int c = 0; c < 100; ++c) acc += wr[c] * hv[c];
        sa[tid] = acc;
    }
    __syncthreads();
    if (tid == 0) {
        float mxv = -1e30f; for (int i = 0; i < 100; ++i) mxv = fmaxf(mxv, st[i]);
        float s = 0.f; for (int i = 0; i < 100; ++i) s += expf(st[i] - mxv);
        redm[0] = mxv; reds[0] = s;
    }
    if (tid == 1) {
        float mxv = -1e30f; for (int i = 0; i < 96; ++i) mxv = fmaxf(mxv, sa[i]);
        float s = 0.f; for (int i = 0; i < 96; ++i) s += expf(sa[i] - mxv);
        redm[1] = mxv; reds[1] = s;
    }
    __syncthreads();
    if (tid < 100) atba[tid] = expf(st[tid] - redm[0]) / reds[0] * hv[tid];
    if (tid < 96)  aat[tid]  = expf(sa[tid] - redm[1]) / reds[1] * xg[tid];
    __syncthreads();
    float a0 = 0.f, a1 = 0.f, a2 = 0.f, a3 = 0.f;
    for (int col = tid; col < 3268; col += 128) {
        float f;
        if (col < 1536)      f = afeat[b * 1536 + col];
        else if (col < 3072) f = tfeat[b * 1536 + col - 1536];
        else if (col < 3168) f = aat[col - 3072];
        else                 f = atba[col - 3168];
        a0 += w_e[col] * f;            a1 += w_e[3268 + col] * f;
        a2 += w_e[2 * 3268 + col] * f; a3 += w_e[3 * 3268 + col] * f;
    }
    __shared__ float r4[4][128];
    r4[0][tid] = a0; r4[1][tid] = a1; r4[2][tid] = a2; r4[3][tid] = a3;
    __syncthreads();
    if (tid < 4) {
        float s = 0.f;
        for (int i = 0; i < 128; ++i) s += r4[tid][i];
        out[b * 4 + tid] = s + b_e[tid];
    }
}

// =====================================================================
extern "C" void kernel_launch(void* const* d_in, const int* in_sizes, int n_in,
                              void* d_out, int out_size, void* d_ws, size_t ws_size,
                              hipStream_t stream) {
    (void)in_sizes; (void)n_in; (void)out_size; (void)ws_size;
    const float* mfcc_t = (const float*)d_in[0];
    const float* mfcc_f = (const float*)d_in[1];
    const float* mfcc_c = (const float*)d_in[2];
    const int*   tokens = (const int*)d_in[3];
    const float *w1a = (const float*)d_in[5],  *b1a = (const float*)d_in[6],
                *g1a = (const float*)d_in[7],  *be1a = (const float*)d_in[8],
                *m1a = (const float*)d_in[9],  *v1a = (const float*)d_in[10];
    const float *w1b = (const float*)d_in[11], *b1b = (const float*)d_in[12],
                *g1b = (const float*)d_in[13], *be1b = (const float*)d_in[14],
                *m1b = (const float*)d_in[15], *v1b = (const float*)d_in[16];
    const float *w2 = (const float*)d_in[17], *b2 = (const float*)d_in[18],
                *g2 = (const float*)d_in[19], *be2 = (const float*)d_in[20],
                *m2 = (const float*)d_in[21], *v2 = (const float*)d_in[22];
    const float *w3 = (const float*)d_in[23], *b3 = (const float*)d_in[24],
                *g3 = (const float*)d_in[25], *be3 = (const float*)d_in[26],
                *m3 = (const float*)d_in[27], *v3 = (const float*)d_in[28];
    const float *w4 = (const float*)d_in[29], *b4 = (const float*)d_in[30],
                *g4 = (const float*)d_in[31], *be4 = (const float*)d_in[32],
                *m4 = (const float*)d_in[33], *v4 = (const float*)d_in[34];
    const float *wq_a1 = (const float*)d_in[35], *bq_a1 = (const float*)d_in[36],
                *wk_a1 = (const float*)d_in[37], *bk_a1 = (const float*)d_in[38],
                *wv_a1 = (const float*)d_in[39], *bv_a1 = (const float*)d_in[40];
    const float *wq_a2 = (const float*)d_in[41], *bq_a2 = (const float*)d_in[42],
                *wk_a2 = (const float*)d_in[43], *bk_a2 = (const float*)d_in[44],
                *wv_a2 = (const float*)d_in[45], *bv_a2 = (const float*)d_in[46];
    const float *emb  = (const float*)d_in[47];
    const float *w_ih = (const float*)d_in[48], *w_hh = (const float*)d_in[49],
                *b_ih = (const float*)d_in[50], *b_hh = (const float*)d_in[51];
    const float *wq_t1 = (const float*)d_in[52], *bq_t1 = (const float*)d_in[53],
                *wk_t1 = (const float*)d_in[54], *bk_t1 = (const float*)d_in[55],
                *wv_t1 = (const float*)d_in[56], *bv_t1 = (const float*)d_in[57];
    const float *wq_t2 = (const float*)d_in[58], *bq_t2 = (const float*)d_in[59],
                *wk_t2 = (const float*)d_in[60], *bk_t2 = (const float*)d_in[61],
                *wv_t2 = (const float*)d_in[62], *bv_t2 = (const float*)d_in[63];
    const float *w_fa = (const float*)d_in[64], *b_fa = (const float*)d_in[65],
                *w_ft = (const float*)d_in[66], *b_ft = (const float*)d_in[67],
                *w_e  = (const float*)d_in[68], *b_e  = (const float*)d_in[69];

    float* ws = (float*)d_ws;
    const size_t Z0 = 0;                 // c2 -> c3 -> x4
    const size_t Z1 = 22091776ull;       // x1 -> p2 -> p3 -> GI
    const size_t OUTS  = 34072576ull;    // conv-wT (early) then GRU outputs
    const size_t AFEAT = 34712576ull;
    const size_t TFEAT = 34909184ull;
    const size_t XGAP  = 35105792ull;
    const size_t WT    = 35118080ull;
    float* X1 = ws + Z1;
    float* C2 = ws + Z0;  float* P2 = ws + Z1;
    float* C3 = ws + Z0;  float* P3 = ws + Z1;
    float* X4 = ws + Z0;  float* GI = ws + Z1;
    float* outs  = ws + OUTS;
    float* afeat = ws + AFEAT;
    float* tfeat = ws + TFEAT;
    float* xgap  = ws + XGAP;
    float* wqa1t = ws + WT;
    float* wka1t = wqa1t + 73728; float* wva1t = wka1t + 73728;
    float* wqa2t = wva1t + 73728; float* wka2t = wqa2t + 73728; float* wva2t = wka2t + 73728;
    // conv weight transposes parked in the (still dead) GRU outs region
    float* wT2 = outs;            //  6,912
    float* wT3 = outs + 6912;     // 18,432
    float* wT4 = outs + 25344;    // 55,296

    // ----- all weight transposes in ONE launch -----
    TPack tp;
    tp.d[0] = {wq_a1, wqa1t, 96, 96, 73728};
    tp.d[1] = {wk_a1, wka1t, 96, 96, 73728};
    tp.d[2] = {wv_a1, wva1t, 96, 96, 73728};
    tp.d[3] = {wq_a2, wqa2t, 96, 96, 73728};
    tp.d[4] = {wk_a2, wka2t, 96, 96, 73728};
    tp.d[5] = {wv_a2, wva2t, 96, 96, 73728};
    tp.d[6] = {w2, wT2, 32, 216, 6912};
    tp.d[7] = {w3, wT3, 64, 288, 18432};
    tp.d[8] = {w4, wT4, 96, 576, 55296};
    k_transpose_pack<<<dim3(288, 9), 256, 0, stream>>>(tp);

    // ----- fused stem (conv1 x3 + BN + ReLU + resize + concat) -----
    k_stem<<<46800, 256, 0, stream>>>(mfcc_t, mfcc_f, mfcc_c,
        w1a, b1a, g1a, be1a, m1a, v1a,
        w1b, b1b, g1b, be1b, m1b, v1b, X1, 11980800);
    k_conv3x3_tiled<24, 8, 25, 156, 9, 6><<<dim3(128, 3, 4), 256, 0, stream>>>(
        X1, wT2, b2, g2, be2, m2, v2, C2, 32);
    k_maxpool<<<14976, 256, 0, stream>>>(C2, P2, 32, 25, 156, 12, 78, 3833856);
    k_conv3x3_tiled<32, 8, 12, 78, 12, 4><<<dim3(128, 1, 8), 256, 0, stream>>>(
        P2, wT3, b3, g3, be3, m3, v3, C3, 64);
    k_maxpool<<<7488, 256, 0, stream>>>(C3, P3, 64, 12, 78, 6, 39, 1916928);
    k_conv3x3_tiled<64, 16, 6, 39, 6, 1><<<dim3(128, 1, 12), 256, 0, stream>>>(
        P3, wT4, b4, g4, be4, m4, v4, X4, 96);

    // ----- audio attention (+GAP folded in) -----
    k_audio_attn<<<dim3(kB, 8, 2), 128, 0, stream>>>(X4,
        wqa1t, bq_a1, wka1t, bk_a1, wva1t, bv_a1,
        wqa2t, bq_a2, wka2t, bk_a2, wva2t, bv_a2, afeat, xgap);

    // ----- text branch -----
    k_gi<<<kB * kT / 8, 320, 0, stream>>>(tokens, emb, w_ih, b_ih, GI);
    k_gru_all<<<kB, 320, 0, stream>>>(GI, w_hh, b_hh, outs);
    k_text_attn<<<dim3(kB, 2, 8), 128, 0, stream>>>(outs,
        wq_t1, bq_t1, wk_t1, bk_t1, wv_t1, bv_t1,
        wq_t2, bq_t2, wk_t2, bk_t2, wv_t2, bv_t2, tfeat);

    // ----- fusion + logits -----
    k_final<<<kB, 128, 0, stream>>>(xgap, outs, afeat, tfeat,
                                    w_fa, b_fa, w_ft, b_ft, w_e, b_e, (float*)d_out);
}

// Round 5
// 1697.763 us; speedup vs baseline: 2.6183x; 1.0937x over previous
//
#include <hip/hip_runtime.h>
#include <math.h>

// ---------------- constants ----------------
static constexpr int kB = 128;
static constexpr int kT = 50;

// ---------- packed transpose [N][O][C] -> [N][C][O], 9 segments, one launch ----------
struct TDesc { const float* src; float* dst; int O; int C; int total; };
struct TPack { TDesc d[9]; };
__global__ void k_transpose_pack(TPack p) {
    TDesc t = p.d[blockIdx.y];
    int idx = blockIdx.x * 256 + threadIdx.x;
    if (idx >= t.total) return;
    int o = idx % t.O; int r = idx / t.O; int c = r % t.C; int n = r / t.C;
    t.dst[idx] = t.src[((size_t)n * t.O + o) * t.C + c];
}

// ---------- fused stem: conv1{a,b,b} + BN + ReLU + bilinear resize + concat ----------
__global__ void k_stem(const float* __restrict__ mt, const float* __restrict__ mf,
                       const float* __restrict__ mc,
                       const float* __restrict__ w1a, const float* __restrict__ b1a,
                       const float* __restrict__ g1a, const float* __restrict__ be1a,
                       const float* __restrict__ m1a, const float* __restrict__ v1a,
                       const float* __restrict__ w1b, const float* __restrict__ b1b,
                       const float* __restrict__ g1b, const float* __restrict__ be1b,
                       const float* __restrict__ m1b, const float* __restrict__ v1b,
                       float* __restrict__ out, int total) {
    int idx = blockIdx.x * blockDim.x + threadIdx.x;
    if (idx >= total) return;
    int ox = idx % 156; int t = idx / 156;
    int oy = t % 25; t /= 25;
    int ch = t % 24; int b = t / 24;
    int grp = ch >> 3, c = ch & 7;
    const float* src; int Hc, Wc;
    const float *wb, *cb, *g, *be, *m, *v;
    if (grp == 0) { src = mt; Hc = 196; Wc = 39; wb = w1a + c * 10;
                    cb = b1a; g = g1a; be = be1a; m = m1a; v = v1a; }
    else          { src = (grp == 1 ? mf : mc); Hc = 199; Wc = 35; wb = w1b + c * 12;
                    cb = b1b; g = g1b; be = be1b; m = m1b; v = v1b; }
    float s = g[c] * rsqrtf(v[c] + 1e-5f);
    float bias = (cb[c] - m[c]) * s + be[c];
    float sy = (oy + 0.5f) * ((float)Hc / 25.f) - 0.5f;
    float sx = (ox + 0.5f) * ((float)Wc / 156.f) - 0.5f;
    float fy0 = floorf(sy), fx0 = floorf(sx);
    float fy = sy - fy0, fx = sx - fx0;
    int y0 = (int)fy0, x0 = (int)fx0;
    int y0c = min(max(y0, 0), Hc - 1), y1c = min(max(y0 + 1, 0), Hc - 1);
    int x0c = min(max(x0, 0), Wc - 1), x1c = min(max(x0 + 1, 0), Wc - 1);
    const float* p = src + (size_t)b * 8000;   // 200*40
    float t00 = 0.f, t01 = 0.f, t10 = 0.f, t11 = 0.f;
    if (grp == 0) {
        #pragma unroll
        for (int ky = 0; ky < 5; ++ky)
            #pragma unroll
            for (int kx = 0; kx < 2; ++kx) {
                float wv = wb[ky * 2 + kx];
                t00 += p[(y0c + ky) * 40 + x0c + kx] * wv;
                t01 += p[(y0c + ky) * 40 + x1c + kx] * wv;
                t10 += p[(y1c + ky) * 40 + x0c + kx] * wv;
                t11 += p[(y1c + ky) * 40 + x1c + kx] * wv;
            }
    } else {
        #pragma unroll
        for (int ky = 0; ky < 2; ++ky)
            #pragma unroll
            for (int kx = 0; kx < 6; ++kx) {
                float wv = wb[ky * 6 + kx];
                t00 += p[(y0c + ky) * 40 + x0c + kx] * wv;
                t01 += p[(y0c + ky) * 40 + x1c + kx] * wv;
                t10 += p[(y1c + ky) * 40 + x0c + kx] * wv;
                t11 += p[(y1c + ky) * 40 + x1c + kx] * wv;
            }
    }
    float r00 = fmaxf(t00 * s + bias, 0.f), r01 = fmaxf(t01 * s + bias, 0.f);
    float r10 = fmaxf(t10 * s + bias, 0.f), r11 = fmaxf(t11 * s + bias, 0.f);
    out[idx] = r00 * (1.f - fy) * (1.f - fx) + r01 * (1.f - fy) * fx
             + r10 * fy * (1.f - fx) + r11 * fy * fx;
}

// ---------- LDS-tiled 3x3 conv, pad 1, fused BN(eval) + ReLU ----------
template<int CIN, int CI_T, int H, int W, int ROWS, int NPX>
__global__ void __launch_bounds__(256) k_conv3x3_tiled(
    const float* __restrict__ in, const float* __restrict__ wT,
    const float* __restrict__ cb, const float* __restrict__ g,
    const float* __restrict__ be, const float* __restrict__ m,
    const float* __restrict__ v, float* __restrict__ out, int COUT) {
    constexpr int WP = W + 2;
    constexpr int RP = ROWS + 2;
    constexpr int STAGE = CI_T * RP * WP;
    __shared__ float sx[STAGE];
    __shared__ float sw[CI_T * 9 * 8];
    const int b = blockIdx.x, rt = blockIdx.y, oc0 = blockIdx.z * 8;
    const int row0 = rt * ROWS;
    const int tid = threadIdx.x;

    int off[NPX]; bool val[NPX];
    #pragma unroll
    for (int j = 0; j < NPX; ++j) {
        int px = tid + j * 256;
        int oy = px / W, ox = px - oy * W;
        bool ok = (px < ROWS * W) && (row0 + oy < H);
        val[j] = ok;
        off[j] = ok ? (oy * WP + ox) : 0;
    }

    float acc[NPX][8];
    #pragma unroll
    for (int j = 0; j < NPX; ++j)
        #pragma unroll
        for (int o = 0; o < 8; ++o) acc[j][o] = 0.f;

    for (int c0 = 0; c0 < CIN; c0 += CI_T) {
        __syncthreads();
        for (int e = tid; e < STAGE; e += 256) {
            int ci = e / (RP * WP);
            int rem = e - ci * RP * WP;
            int r = rem / WP;
            int xx = rem - r * WP;
            int iy = row0 - 1 + r;
            int ix = xx - 1;
            float vv = 0.f;
            if (iy >= 0 && iy < H && ix >= 0 && ix < W)
                vv = in[((size_t)(b * CIN + c0 + ci) * H + iy) * W + ix];
            sx[e] = vv;
        }
        for (int e = tid; e < CI_T * 9 * 8; e += 256) {
            int rk = e >> 3;
            int o = e & 7;
            sw[e] = wT[((size_t)c0 * 9 + rk) * COUT + oc0 + o];
        }
        __syncthreads();
        #pragma unroll 1
        for (int cl = 0; cl < CI_T; ++cl) {
            const float* sxc = sx + cl * RP * WP;
            #pragma unroll
            for (int k = 0; k < 9; ++k) {
                const int ky = k / 3, kx = k % 3;
                const float4 wa = *(const float4*)(sw + (cl * 9 + k) * 8);
                const float4 wb = *(const float4*)(sw + (cl * 9 + k) * 8 + 4);
                #pragma unroll
                for (int j = 0; j < NPX; ++j) {
                    float xv = sxc[off[j] + ky * WP + kx];
                    acc[j][0] += xv * wa.x; acc[j][1] += xv * wa.y;
                    acc[j][2] += xv * wa.z; acc[j][3] += xv * wa.w;
                    acc[j][4] += xv * wb.x; acc[j][5] += xv * wb.y;
                    acc[j][6] += xv * wb.z; acc[j][7] += xv * wb.w;
                }
            }
        }
    }
    float sc[8], bi[8];
    #pragma unroll
    for (int o = 0; o < 8; ++o) {
        float s = g[oc0 + o] * rsqrtf(v[oc0 + o] + 1e-5f);
        sc[o] = s; bi[o] = (cb[oc0 + o] - m[oc0 + o]) * s + be[oc0 + o];
    }
    #pragma unroll
    for (int j = 0; j < NPX; ++j) if (val[j]) {
        int px = tid + j * 256;
        int oy = row0 + px / W, ox = px % W;
        #pragma unroll
        for (int o = 0; o < 8; ++o)
            out[((size_t)(b * COUT + oc0 + o) * H + oy) * W + ox] =
                fmaxf(acc[j][o] * sc[o] + bi[o], 0.f);
    }
}

// ---------- 2x2 maxpool stride 2 (VALID) ----------
__global__ void k_maxpool(const float* __restrict__ in, float* __restrict__ out,
                          int C, int Hin, int Win, int Hout, int Wout, int total) {
    int idx = blockIdx.x * blockDim.x + threadIdx.x;
    if (idx >= total) return;
    int ox = idx % Wout; int t = idx / Wout;
    int oy = t % Hout; t /= Hout;
    int c = t % C; int b = t / C;
    const float* p = in + ((size_t)(b * C + c) * Hin + 2 * oy) * Win + 2 * ox;
    float m0 = fmaxf(p[0], p[1]);
    float m1 = fmaxf(p[Win], p[Win + 1]);
    out[idx] = fmaxf(m0, m1);
}

// ---------- fused audio attention (both stages) + spatial GAP ----------
// R2 structure (measured 655us, zero bank conflicts): stride-26 xt, sb score
// matrix in LDS. Deltas vs R2: bias-init accumulators, GAP folded into
// (n==0,stage==0) blocks, two-stage softmax reduce (serial 96 -> 24+4), __expf.
__global__ void __launch_bounds__(128) k_audio_attn(
    const float* __restrict__ x,
    const float* __restrict__ wq1, const float* __restrict__ bq1,
    const float* __restrict__ wk1, const float* __restrict__ bk1,
    const float* __restrict__ wv1, const float* __restrict__ bv1,
    const float* __restrict__ wq2, const float* __restrict__ bq2,
    const float* __restrict__ wk2, const float* __restrict__ bk2,
    const float* __restrict__ wv2, const float* __restrict__ bv2,
    float* __restrict__ afeat, float* __restrict__ xgap) {
    int b = blockIdx.x, n = blockIdx.y, stage = blockIdx.z;
    const float* wq = stage ? wq2 : wq1; const float* bq = stage ? bq2 : bq1;
    const float* wk = stage ? wk2 : wk1; const float* bk = stage ? bk2 : bk1;
    const float* wv = stage ? wv2 : wv1; const float* bv = stage ? bv2 : bv1;
    __shared__ float xt[96 * 26];
    __shared__ float sb[96 * 26];
    __shared__ float pmax[4][26], psum[4][26];
    __shared__ float mx[26], sm[26];
    int tid = threadIdx.x;
    bool act = tid < 96;
    int o = act ? tid : 0;
    float bqv = act ? bq[n * 96 + tid] : 0.f;
    float bkv = act ? bk[n * 96 + tid] : 0.f;
    float bvv = act ? bv[n * 96 + tid] : 0.f;
    const float* wqb = wq + n * 9216 + o;   // [c][o] layout -> wqb[c*96]
    const float* wkb = wk + n * 9216 + o;
    const float* wvb = wv + n * 9216 + o;
    const bool do_gap = (n == 0 && stage == 0);
    float accO = 0.f, xsum = 0.f;
    const float* xb = x + (size_t)b * 96 * 234;
    for (int tile = 0; tile < 9; ++tile) {
        int p0 = tile * 26;
        __syncthreads();
        for (int e = tid; e < 2496; e += 128) {
            int c = e / 26, pp = e - c * 26;
            xt[e] = xb[c * 234 + p0 + pp];
        }
        __syncthreads();
        if (do_gap && act) {
            const float* xr = xt + o * 26;
            #pragma unroll
            for (int p = 0; p < 26; ++p) xsum += xr[p];
        }
        float aq[26], ak[26], av[26];
        #pragma unroll
        for (int p = 0; p < 26; ++p) { aq[p] = bqv; ak[p] = bkv; av[p] = bvv; }
        for (int c = 0; c < 96; ++c) {
            float wqv = wqb[c * 96], wkv = wkb[c * 96], wvv2 = wvb[c * 96];
            const float* xr = xt + c * 26;
            #pragma unroll
            for (int p = 0; p < 26; ++p) {
                float xv = xr[p];
                aq[p] += wqv * xv; ak[p] += wkv * xv; av[p] += wvv2 * xv;
            }
        }
        if (act) {
            #pragma unroll
            for (int p = 0; p < 26; ++p)
                sb[o * 26 + p] = aq[p] * ak[p];
        }
        __syncthreads();
        // two-stage max over o (96 = 4 chunks of 24)
        if (tid < 104) {
            int p = tid % 26, ch = tid / 26;
            int o0 = ch * 24;
            float m_ = -1e30f;
            for (int q = 0; q < 24; ++q) m_ = fmaxf(m_, sb[(o0 + q) * 26 + p]);
            pmax[ch][p] = m_;
        }
        __syncthreads();
        if (tid < 26)
            mx[tid] = fmaxf(fmaxf(pmax[0][tid], pmax[1][tid]),
                            fmaxf(pmax[2][tid], pmax[3][tid]));
        __syncthreads();
        // two-stage sum of exp
        if (tid < 104) {
            int p = tid % 26, ch = tid / 26;
            int o0 = ch * 24;
            float mv = mx[p];
            float s_ = 0.f;
            for (int q = 0; q < 24; ++q) s_ += __expf(sb[(o0 + q) * 26 + p] - mv);
            psum[ch][p] = s_;
        }
        __syncthreads();
        if (tid < 26)
            sm[tid] = psum[0][tid] + psum[1][tid] + psum[2][tid] + psum[3][tid];
        __syncthreads();
        if (act) {
            #pragma unroll
            for (int p = 0; p < 26; ++p)
                accO += __expf(sb[o * 26 + p] - mx[p]) / sm[p] * av[p];
        }
    }
    if (act) afeat[b * 1536 + n * 192 + stage * 96 + tid] = accO * (1.f / 234.f);
    if (do_gap && act) xgap[b * 96 + tid] = xsum * (1.f / 234.f);
}

// ---------- embedding lookup + input-side GRU GEMM, 8 rows/block ----------
__global__ void __launch_bounds__(320) k_gi(const int* __restrict__ tokens,
        const float* __restrict__ emb, const float* __restrict__ w_ih,
        const float* __restrict__ b_ih, float* __restrict__ GI) {
    int r0 = blockIdx.x * 8;
    int tid = threadIdx.x;
    __shared__ float er[8][200];
    for (int e = tid; e < 1600; e += 320) {
        int r = e / 200, c = e - r * 200;
        er[r][c] = emb[(size_t)tokens[r0 + r] * 200 + c];
    }
    __syncthreads();
    if (tid < 300) {
        float acc[8];
        float bv = b_ih[tid];
        #pragma unroll
        for (int r = 0; r < 8; ++r) acc[r] = bv;
        for (int k4 = 0; k4 < 50; ++k4) {
            float4 w4 = *(const float4*)(w_ih + (size_t)tid * 200 + k4 * 4);
            #pragma unroll
            for (int r = 0; r < 8; ++r) {
                float4 x4 = *(const float4*)&er[r][k4 * 4];
                acc[r] += w4.x * x4.x + w4.y * x4.y + w4.z * x4.z + w4.w * x4.w;
            }
        }
        #pragma unroll
        for (int r = 0; r < 8; ++r)
            GI[(size_t)(r0 + r) * 300 + tid] = acc[r];
    }
}

// ---------- whole GRU recurrence in ONE kernel (one block per batch row) ----------
__global__ void __launch_bounds__(320) k_gru_all(const float* __restrict__ GI,
        const float* __restrict__ w_hh, const float* __restrict__ b_hh,
        float* __restrict__ outs) {
    int b = blockIdx.x, tid = threadIdx.x;
    __shared__ float hs[100];
    __shared__ float gH[300];
    float4 wreg[25];
    float bias = 0.f;
    if (tid < 300) {
        bias = b_hh[tid];
        #pragma unroll
        for (int k4 = 0; k4 < 25; ++k4)
            wreg[k4] = *(const float4*)(w_hh + (size_t)tid * 100 + k4 * 4);
    }
    if (tid < 100) hs[tid] = 0.f;
    __syncthreads();
    for (int t = 0; t < kT; ++t) {
        if (tid < 300) {
            float gh = bias;
            #pragma unroll
            for (int k4 = 0; k4 < 25; ++k4) {
                float4 h4 = *(const float4*)&hs[k4 * 4];
                gh += wreg[k4].x * h4.x + wreg[k4].y * h4.y
                    + wreg[k4].z * h4.z + wreg[k4].w * h4.w;
            }
            gH[tid] = gh;
        }
        __syncthreads();
        if (tid < 100) {
            const float* gi = GI + ((size_t)b * kT + t) * 300;
            float r = 1.f / (1.f + expf(-(gi[tid] + gH[tid])));
            float z = 1.f / (1.f + expf(-(gi[100 + tid] + gH[100 + tid])));
            float nn = tanhf(gi[200 + tid] + r * gH[200 + tid]);
            float h2 = (1.f - z) * nn + z * hs[tid];
            hs[tid] = h2;
            outs[((size_t)b * kT + t) * 100 + tid] = h2;
        }
        __syncthreads();
    }
}

// ---------- fused text attention (both stages), t-tiled, shuffle softmax ----------
__global__ void __launch_bounds__(128) k_text_attn(const float* __restrict__ outs,
    const float* __restrict__ wq1, const float* __restrict__ bq1,
    const float* __restrict__ wk1, const float* __restrict__ bk1,
    const float* __restrict__ wv1, const float* __restrict__ bv1,
    const float* __restrict__ wq2, const float* __restrict__ bq2,
    const float* __restrict__ wk2, const float* __restrict__ bk2,
    const float* __restrict__ wv2, const float* __restrict__ bv2,
    float* __restrict__ tfeat) {
    int b = blockIdx.x, stage = blockIdx.y, n = blockIdx.z;
    const float* wq = stage ? wq2 : wq1; const float* bq = stage ? bq2 : bq1;
    const float* wk = stage ? wk2 : wk1; const float* bk = stage ? bk2 : bk1;
    const float* wv = stage ? wv2 : wv1; const float* bv = stage ? bv2 : bv1;
    int tid = threadIdx.x;
    bool act = tid < 96;
    int oo = act ? tid : 0;
    const float* wqr = wq + ((size_t)n * 96 + oo) * 100;
    const float* wkr = wk + ((size_t)n * 96 + oo) * 100;
    const float* wvr = wv + ((size_t)n * 96 + oo) * 100;
    float bqv = act ? bq[n * 96 + tid] : 0.f;
    float bkv = act ? bk[n * 96 + tid] : 0.f;
    float bvv = act ? bv[n * 96 + tid] : 0.f;
    __shared__ float rows[10][100];
    __shared__ float wredM[2][10], wredS[2][10];
    float acc = 0.f;
    int wave = tid >> 6, lane = tid & 63;
    for (int tile = 0; tile < 5; ++tile) {
        int t0 = tile * 10;
        __syncthreads();
        for (int e = tid; e < 1000; e += 128) {
            int tt = e / 100, c = e - tt * 100;
            rows[tt][c] = outs[((size_t)b * kT + t0 + tt) * 100 + c];
        }
        __syncthreads();
        float q[10], k[10], v[10];
        #pragma unroll
        for (int tt = 0; tt < 10; ++tt) { q[tt] = bqv; k[tt] = bkv; v[tt] = bvv; }
        for (int c4 = 0; c4 < 25; ++c4) {
            float4 aq = *(const float4*)(wqr + c4 * 4);
            float4 ak = *(const float4*)(wkr + c4 * 4);
            float4 av = *(const float4*)(wvr + c4 * 4);
            #pragma unroll
            for (int tt = 0; tt < 10; ++tt) {
                float4 x4 = *(const float4*)&rows[tt][c4 * 4];
                q[tt] += aq.x * x4.x + aq.y * x4.y + aq.z * x4.z + aq.w * x4.w;
                k[tt] += ak.x * x4.x + ak.y * x4.y + ak.z * x4.z + ak.w * x4.w;
                v[tt] += av.x * x4.x + av.y * x4.y + av.z * x4.z + av.w * x4.w;
            }
        }
        float s[10], e_[10];
        #pragma unroll
        for (int tt = 0; tt < 10; ++tt) s[tt] = act ? q[tt] * k[tt] : -1e30f;
        #pragma unroll
        for (int tt = 0; tt < 10; ++tt) {
            float m = s[tt];
            #pragma unroll
            for (int off = 1; off < 64; off <<= 1) m = fmaxf(m, __shfl_xor(m, off));
            if (lane == 0) wredM[wave][tt] = m;
        }
        __syncthreads();
        #pragma unroll
        for (int tt = 0; tt < 10; ++tt) {
            float mx = fmaxf(wredM[0][tt], wredM[1][tt]);
            e_[tt] = expf(s[tt] - mx);
        }
        #pragma unroll
        for (int tt = 0; tt < 10; ++tt) {
            float sm = e_[tt];
            #pragma unroll
            for (int off = 1; off < 64; off <<= 1) sm += __shfl_xor(sm, off);
            if (lane == 0) wredS[wave][tt] = sm;
        }
        __syncthreads();
        #pragma unroll
        for (int tt = 0; tt < 10; ++tt) {
            float sm = wredS[0][tt] + wredS[1][tt];
            acc += e_[tt] / sm * v[tt];
        }
    }
    if (act) tfeat[b * 1536 + stage * 768 + n * 96 + tid] = acc;
}

// ---------- cross-modal gated fusion + final logits ----------
__global__ void __launch_bounds__(128) k_final(const float* __restrict__ xgap,
    const float* __restrict__ outs, const float* __restrict__ afeat,
    const float* __restrict__ tfeat,
    const float* __restrict__ w_fa, const float* __restrict__ b_fa,
    const float* __restrict__ w_ft, const float* __restrict__ b_ft,
    const float* __restrict__ w_e, const float* __restrict__ b_e,
    float* __restrict__ out) {
    int b = blockIdx.x; int tid = threadIdx.x;
    __shared__ float xg[96], hv[100], st[100], sa[96], aat[96], atba[100];
    __shared__ float redm[2], reds[2];
    if (tid < 96) xg[tid] = xgap[b * 96 + tid];
    if (tid < 100) hv[tid] = outs[(size_t)(b * kT + kT - 1) * 100 + tid];
    __syncthreads();
    if (tid < 100) {
        float acc = b_fa[tid];
        const float* wr = w_fa + tid * 96;
        for (int c = 0; c < 96; ++c) acc += wr[c] * xg[c];
        st[tid] = acc;
    }
    if (tid < 96) {
        float acc = b_ft[tid];
        const float* wr = w_ft + tid * 100;
        for (int c = 0; c < 100; ++c) acc += wr[c] * hv[c];
        sa[tid] = acc;
    }
    __syncthreads();
    if (tid == 0) {
        float mxv = -1e30f; for (int i = 0; i < 100; ++i) mxv = fmaxf(mxv, st[i]);
        float s = 0.f; for (int i = 0; i < 100; ++i) s += expf(st[i] - mxv);
        redm[0] = mxv; reds[0] = s;
    }
    if (tid == 1) {
        float mxv = -1e30f; for (int i = 0; i < 96; ++i) mxv = fmaxf(mxv, sa[i]);
        float s = 0.f; for (int i = 0; i < 96; ++i) s += expf(sa[i] - mxv);
        redm[1] = mxv; reds[1] = s;
    }
    __syncthreads();
    if (tid < 100) atba[tid] = expf(st[tid] - redm[0]) / reds[0] * hv[tid];
    if (tid < 96)  aat[tid]  = expf(sa[tid] - redm[1]) / reds[1] * xg[tid];
    __syncthreads();
    float a0 = 0.f, a1 = 0.f, a2 = 0.f, a3 = 0.f;
    for (int col = tid; col < 3268; col += 128) {
        float f;
        if (col < 1536)      f = afeat[b * 1536 + col];
        else if (col < 3072) f = tfeat[b * 1536 + col - 1536];
        else if (col < 3168) f = aat[col - 3072];
        else                 f = atba[col - 3168];
        a0 += w_e[col] * f;            a1 += w_e[3268 + col] * f;
        a2 += w_e[2 * 3268 + col] * f; a3 += w_e[3 * 3268 + col] * f;
    }
    __shared__ float r4[4][128];
    r4[0][tid] = a0; r4[1][tid] = a1; r4[2][tid] = a2; r4[3][tid] = a3;
    __syncthreads();
    if (tid < 4) {
        float s = 0.f;
        for (int i = 0; i < 128; ++i) s += r4[tid][i];
        out[b * 4 + tid] = s + b_e[tid];
    }
}

// =====================================================================
extern "C" void kernel_launch(void* const* d_in, const int* in_sizes, int n_in,
                              void* d_out, int out_size, void* d_ws, size_t ws_size,
                              hipStream_t stream) {
    (void)in_sizes; (void)n_in; (void)out_size; (void)ws_size;
    const float* mfcc_t = (const float*)d_in[0];
    const float* mfcc_f = (const float*)d_in[1];
    const float* mfcc_c = (const float*)d_in[2];
    const int*   tokens = (const int*)d_in[3];
    const float *w1a = (const float*)d_in[5],  *b1a = (const float*)d_in[6],
                *g1a = (const float*)d_in[7],  *be1a = (const float*)d_in[8],
                *m1a = (const float*)d_in[9],  *v1a = (const float*)d_in[10];
    const float *w1b = (const float*)d_in[11], *b1b = (const float*)d_in[12],
                *g1b = (const float*)d_in[13], *be1b = (const float*)d_in[14],
                *m1b = (const float*)d_in[15], *v1b = (const float*)d_in[16];
    const float *w2 = (const float*)d_in[17], *b2 = (const float*)d_in[18],
                *g2 = (const float*)d_in[19], *be2 = (const float*)d_in[20],
                *m2 = (const float*)d_in[21], *v2 = (const float*)d_in[22];
    const float *w3 = (const float*)d_in[23], *b3 = (const float*)d_in[24],
                *g3 = (const float*)d_in[25], *be3 = (const float*)d_in[26],
                *m3 = (const float*)d_in[27], *v3 = (const float*)d_in[28];
    const float *w4 = (const float*)d_in[29], *b4 = (const float*)d_in[30],
                *g4 = (const float*)d_in[31], *be4 = (const float*)d_in[32],
                *m4 = (const float*)d_in[33], *v4 = (const float*)d_in[34];
    const float *wq_a1 = (const float*)d_in[35], *bq_a1 = (const float*)d_in[36],
                *wk_a1 = (const float*)d_in[37], *bk_a1 = (const float*)d_in[38],
                *wv_a1 = (const float*)d_in[39], *bv_a1 = (const float*)d_in[40];
    const float *wq_a2 = (const float*)d_in[41], *bq_a2 = (const float*)d_in[42],
                *wk_a2 = (const float*)d_in[43], *bk_a2 = (const float*)d_in[44],
                *wv_a2 = (const float*)d_in[45], *bv_a2 = (const float*)d_in[46];
    const float *emb  = (const float*)d_in[47];
    const float *w_ih = (const float*)d_in[48], *w_hh = (const float*)d_in[49],
                *b_ih = (const float*)d_in[50], *b_hh = (const float*)d_in[51];
    const float *wq_t1 = (const float*)d_in[52], *bq_t1 = (const float*)d_in[53],
                *wk_t1 = (const float*)d_in[54], *bk_t1 = (const float*)d_in[55],
                *wv_t1 = (const float*)d_in[56], *bv_t1 = (const float*)d_in[57];
    const float *wq_t2 = (const float*)d_in[58], *bq_t2 = (const float*)d_in[59],
                *wk_t2 = (const float*)d_in[60], *bk_t2 = (const float*)d_in[61],
                *wv_t2 = (const float*)d_in[62], *bv_t2 = (const float*)d_in[63];
    const float *w_fa = (const float*)d_in[64], *b_fa = (const float*)d_in[65],
                *w_ft = (const float*)d_in[66], *b_ft = (const float*)d_in[67],
                *w_e  = (const float*)d_in[68], *b_e  = (const float*)d_in[69];

    float* ws = (float*)d_ws;
    const size_t Z0 = 0;                 // c2 -> c3 -> x4
    const size_t Z1 = 22091776ull;       // x1 -> p2 -> p3 -> GI
    const size_t OUTS  = 34072576ull;    // conv-wT (early) then GRU outputs
    const size_t AFEAT = 34712576ull;
    const size_t TFEAT = 34909184ull;
    const size_t XGAP  = 35105792ull;
    const size_t WT    = 35118080ull;
    float* X1 = ws + Z1;
    float* C2 = ws + Z0;  float* P2 = ws + Z1;
    float* C3 = ws + Z0;  float* P3 = ws + Z1;
    float* X4 = ws + Z0;  float* GI = ws + Z1;
    float* outs  = ws + OUTS;
    float* afeat = ws + AFEAT;
    float* tfeat = ws + TFEAT;
    float* xgap  = ws + XGAP;
    float* wqa1t = ws + WT;
    float* wka1t = wqa1t + 73728; float* wva1t = wka1t + 73728;
    float* wqa2t = wva1t + 73728; float* wka2t = wqa2t + 73728; float* wva2t = wka2t + 73728;
    // conv weight transposes parked in the (still dead) GRU outs region
    float* wT2 = outs;            //  6,912
    float* wT3 = outs + 6912;     // 18,432
    float* wT4 = outs + 25344;    // 55,296

    // ----- all weight transposes in ONE launch -----
    TPack tp;
    tp.d[0] = {wq_a1, wqa1t, 96, 96, 73728};
    tp.d[1] = {wk_a1, wka1t, 96, 96, 73728};
    tp.d[2] = {wv_a1, wva1t, 96, 96, 73728};
    tp.d[3] = {wq_a2, wqa2t, 96, 96, 73728};
    tp.d[4] = {wk_a2, wka2t, 96, 96, 73728};
    tp.d[5] = {wv_a2, wva2t, 96, 96, 73728};
    tp.d[6] = {w2, wT2, 32, 216, 6912};
    tp.d[7] = {w3, wT3, 64, 288, 18432};
    tp.d[8] = {w4, wT4, 96, 576, 55296};
    k_transpose_pack<<<dim3(288, 9), 256, 0, stream>>>(tp);

    // ----- fused stem (conv1 x3 + BN + ReLU + resize + concat) -----
    k_stem<<<46800, 256, 0, stream>>>(mfcc_t, mfcc_f, mfcc_c,
        w1a, b1a, g1a, be1a, m1a, v1a,
        w1b, b1b, g1b, be1b, m1b, v1b, X1, 11980800);
    k_conv3x3_tiled<24, 8, 25, 156, 9, 6><<<dim3(128, 3, 4), 256, 0, stream>>>(
        X1, wT2, b2, g2, be2, m2, v2, C2, 32);
    k_maxpool<<<14976, 256, 0, stream>>>(C2, P2, 32, 25, 156, 12, 78, 3833856);
    k_conv3x3_tiled<32, 8, 12, 78, 12, 4><<<dim3(128, 1, 8), 256, 0, stream>>>(
        P2, wT3, b3, g3, be3, m3, v3, C3, 64);
    k_maxpool<<<7488, 256, 0, stream>>>(C3, P3, 64, 12, 78, 6, 39, 1916928);
    k_conv3x3_tiled<64, 16, 6, 39, 6, 1><<<dim3(128, 1, 12), 256, 0, stream>>>(
        P3, wT4, b4, g4, be4, m4, v4, X4, 96);

    // ----- audio attention (+GAP folded in) -----
    k_audio_attn<<<dim3(kB, 8, 2), 128, 0, stream>>>(X4,
        wqa1t, bq_a1, wka1t, bk_a1, wva1t, bv_a1,
        wqa2t, bq_a2, wka2t, bk_a2, wva2t, bv_a2, afeat, xgap);

    // ----- text branch -----
    k_gi<<<kB * kT / 8, 320, 0, stream>>>(tokens, emb, w_ih, b_ih, GI);
    k_gru_all<<<kB, 320, 0, stream>>>(GI, w_hh, b_hh, outs);
    k_text_attn<<<dim3(kB, 2, 8), 128, 0, stream>>>(outs,
        wq_t1, bq_t1, wk_t1, bk_t1, wv_t1, bv_t1,
        wq_t2, bq_t2, wk_t2, bk_t2, wv_t2, bv_t2, tfeat);

    // ----- fusion + logits -----
    k_final<<<kB, 128, 0, stream>>>(xgap, outs, afeat, tfeat,
                                    w_fa, b_fa, w_ft, b_ft, w_e, b_e, (float*)d_out);
}